// Round 1
// baseline (558.460 us; speedup 1.0000x reference)
//
#include <hip/hip_runtime.h>
#include <hip/hip_bf16.h>

// Problem constants
#define LD 512
#define LS 2048
#define CS 384
#define CH 16
#define NH 12
#define PQ 4
#define PV 8

// ---------------------------------------------------------------------------
// Generic fp32 SGEMM: C[M,N] = A[M,K] @ B[K,N] (+ bias). Row-major.
// BM=BN=64, BK=16, 256 threads, 4x4 micro-tile. M multiple of 64, K multiple
// of 16, N multiple of 4 (partial last N-tile guarded).
// ---------------------------------------------------------------------------
__global__ __launch_bounds__(256) void sgemm_kernel(
    const float* __restrict__ A, const float* __restrict__ B,
    const float* __restrict__ bias, float* __restrict__ C,
    int M, int N, int K)
{
    __shared__ float As[16][68];
    __shared__ float Bs[16][68];
    const int t = threadIdx.x;
    const int tx = t & 15, ty = t >> 4;
    const int m0 = blockIdx.y * 64, n0 = blockIdx.x * 64;

    float acc[4][4];
#pragma unroll
    for (int i = 0; i < 4; ++i)
#pragma unroll
        for (int j = 0; j < 4; ++j) acc[i][j] = 0.f;

    for (int k0 = 0; k0 < K; k0 += 16) {
        // A tile: 64 rows x 16 k
        {
            int r = t >> 2;
            int kk = (t & 3) * 4;
            const float* ap = A + (size_t)(m0 + r) * K + k0 + kk;
            float4 a4 = *(const float4*)ap;
            As[kk + 0][r] = a4.x;
            As[kk + 1][r] = a4.y;
            As[kk + 2][r] = a4.z;
            As[kk + 3][r] = a4.w;
        }
        // B tile: 16 k x 64 n (guard N)
        {
            int kk = t >> 4;
            int nn = (t & 15) * 4;
            int n = n0 + nn;
            float4 b4 = make_float4(0.f, 0.f, 0.f, 0.f);
            if (n < N) b4 = *(const float4*)(B + (size_t)(k0 + kk) * N + n);
            Bs[kk][nn + 0] = b4.x;
            Bs[kk][nn + 1] = b4.y;
            Bs[kk][nn + 2] = b4.z;
            Bs[kk][nn + 3] = b4.w;
        }
        __syncthreads();
#pragma unroll
        for (int kk = 0; kk < 16; ++kk) {
            float4 a4 = *(const float4*)&As[kk][ty * 4];
            float4 b4 = *(const float4*)&Bs[kk][tx * 4];
            acc[0][0] += a4.x * b4.x; acc[0][1] += a4.x * b4.y; acc[0][2] += a4.x * b4.z; acc[0][3] += a4.x * b4.w;
            acc[1][0] += a4.y * b4.x; acc[1][1] += a4.y * b4.y; acc[1][2] += a4.y * b4.z; acc[1][3] += a4.y * b4.w;
            acc[2][0] += a4.z * b4.x; acc[2][1] += a4.z * b4.y; acc[2][2] += a4.z * b4.z; acc[2][3] += a4.z * b4.w;
            acc[3][0] += a4.w * b4.x; acc[3][1] += a4.w * b4.y; acc[3][2] += a4.w * b4.z; acc[3][3] += a4.w * b4.w;
        }
        __syncthreads();
    }
#pragma unroll
    for (int ii = 0; ii < 4; ++ii) {
        int row = m0 + ty * 4 + ii;
#pragma unroll
        for (int jj = 0; jj < 4; ++jj) {
            int n = n0 + tx * 4 + jj;
            if (n < N) {
                float v = acc[ii][jj];
                if (bias) v += bias[n];
                C[(size_t)row * N + n] = v;
            }
        }
    }
}

// ---------------------------------------------------------------------------
// Rotate dst query points: qp_rot = R_dst @ qp_raw + t_dst ; sq_q = sum |qp|^2
// qp_raw: [i][axis*48 + p], p = h*4+pq.  qp_rot: [i][p*3+axis].
// ---------------------------------------------------------------------------
__global__ __launch_bounds__(64) void rot_dst_kernel(
    const float* __restrict__ qp_raw, const float* __restrict__ Rd,
    const float* __restrict__ td, float* __restrict__ qp_rot,
    float* __restrict__ sqq)
{
    const int i = blockIdx.x, t = threadIdx.x;
    __shared__ float part[48];
    if (t < 48) {
        float x = qp_raw[i * 144 + t];
        float y = qp_raw[i * 144 + 48 + t];
        float z = qp_raw[i * 144 + 96 + t];
        const float* R = Rd + i * 9;
        float rx = R[0] * x + R[1] * y + R[2] * z + td[i * 3 + 0];
        float ry = R[3] * x + R[4] * y + R[5] * z + td[i * 3 + 1];
        float rz = R[6] * x + R[7] * y + R[8] * z + td[i * 3 + 2];
        qp_rot[i * 144 + t * 3 + 0] = rx;
        qp_rot[i * 144 + t * 3 + 1] = ry;
        qp_rot[i * 144 + t * 3 + 2] = rz;
        part[t] = rx * rx + ry * ry + rz * rz;
    }
    __syncthreads();
    if (t < NH) sqq[i * NH + t] = part[t * 4] + part[t * 4 + 1] + part[t * 4 + 2] + part[t * 4 + 3];
}

// ---------------------------------------------------------------------------
// Rotate src points -> k_pts (pp<4) and v_pts (pp>=4); sq_k = sum_pq |kp|^2
// kvp_raw: [j][axis*144 + p], p = h*12+pp.
// kp: [j][h*12 + pq*3 + ax], vp: [j][h*24 + pv*3 + ax]
// ---------------------------------------------------------------------------
__global__ __launch_bounds__(192) void rot_src_kernel(
    const float* __restrict__ kvp_raw, const float* __restrict__ Rs,
    const float* __restrict__ ts, float* __restrict__ kp,
    float* __restrict__ vp, float* __restrict__ sqk)
{
    const int j = blockIdx.x, t = threadIdx.x;
    __shared__ float part[48];
    if (t < 144) {
        float x = kvp_raw[j * 432 + t];
        float y = kvp_raw[j * 432 + 144 + t];
        float z = kvp_raw[j * 432 + 288 + t];
        const float* R = Rs + j * 9;
        float rx = R[0] * x + R[1] * y + R[2] * z + ts[j * 3 + 0];
        float ry = R[3] * x + R[4] * y + R[5] * z + ts[j * 3 + 1];
        float rz = R[6] * x + R[7] * y + R[8] * z + ts[j * 3 + 2];
        int h = t / 12, pp = t % 12;
        if (pp < 4) {
            int o = j * 144 + h * 12 + pp * 3;
            kp[o] = rx; kp[o + 1] = ry; kp[o + 2] = rz;
            part[h * 4 + pp] = rx * rx + ry * ry + rz * rz;
        } else {
            int o = j * 288 + h * 24 + (pp - 4) * 3;
            vp[o] = rx; vp[o + 1] = ry; vp[o + 2] = rz;
        }
    }
    __syncthreads();
    if (t < NH) sqk[j * NH + t] = part[t * 4] + part[t * 4 + 1] + part[t * 4 + 2] + part[t * 4 + 3];
}

// ---------------------------------------------------------------------------
// Scores + softmax. Block = (4 dst rows) x (one head), 256 threads.
// Each thread owns j = jc*256 + tid for jc in 0..7 -> logits live in registers.
// Writes a_sd, a_pts, a. pt term via |q-k|^2 = sq_q + sq_k - 2 q.k expansion.
// ---------------------------------------------------------------------------
__global__ __launch_bounds__(256) void score_softmax_kernel(
    const float* __restrict__ qb, const float* __restrict__ kvb,
    const float* __restrict__ qpb, const float* __restrict__ kpb,
    const float* __restrict__ sqq_g, const float* __restrict__ sqk_g,
    const float* __restrict__ dmask, const float* __restrict__ smask,
    const float* __restrict__ head_w,
    float* __restrict__ a_out, float* __restrict__ asd_out,
    float* __restrict__ apts_out)
{
    const int h = blockIdx.y;
    const int i0 = blockIdx.x * 4;
    const int t = threadIdx.x;

    __shared__ float qs[4][32];   // [i][0:16]=q, [16:28]=qp, rest pad
    __shared__ float sqq_s[4];
    __shared__ float dm_s[4];
    __shared__ float red[4][4];   // [wave][i]

    if (t < 128) {
        int i = t >> 5, c = t & 31;
        float v = 0.f;
        if (c < 16) v = qb[(i0 + i) * (NH * CH) + h * CH + c];
        else if (c < 28) v = qpb[(i0 + i) * 144 + h * 12 + (c - 16)];
        qs[i][c] = v;
    } else if (t < 132) {
        int i = t - 128;
        sqq_s[i] = sqq_g[(i0 + i) * NH + h];
        dm_s[i] = dmask[i0 + i];
    }
    const float hwv = log1pf(__expf(head_w[h])) * (1.0f / 6.0f);
    const float s1 = 0.17677669529663687f;  // sqrt(1/32)
    __syncthreads();

    float sreg[4][8];
    float mx[4] = {-3.0e38f, -3.0e38f, -3.0e38f, -3.0e38f};
    const size_t rowbase = ((size_t)h * LD + i0) * LS;

#pragma unroll
    for (int jc = 0; jc < 8; ++jc) {
        const int j = jc * 256 + t;
        const float4* k4 = (const float4*)(kvb + (size_t)j * (2 * NH * CH) + h * 32);
        float4 k0 = k4[0], k1 = k4[1], k2 = k4[2], k3 = k4[3];
        const float4* p4 = (const float4*)(kpb + (size_t)j * 144 + h * 12);
        float4 p0 = p4[0], p1 = p4[1], p2 = p4[2];
        float sqk = sqk_g[j * NH + h];
        float sm = smask[j];
#pragma unroll
        for (int i = 0; i < 4; ++i) {
            const float4* q4 = (const float4*)&qs[i][0];
            float4 q0 = q4[0], q1 = q4[1], q2 = q4[2], q3 = q4[3];
            const float4* r4 = (const float4*)&qs[i][16];
            float4 r0 = r4[0], r1 = r4[1], r2 = r4[2];
            float qk = q0.x * k0.x + q0.y * k0.y + q0.z * k0.z + q0.w * k0.w
                     + q1.x * k1.x + q1.y * k1.y + q1.z * k1.z + q1.w * k1.w
                     + q2.x * k2.x + q2.y * k2.y + q2.z * k2.z + q2.w * k2.w
                     + q3.x * k3.x + q3.y * k3.y + q3.z * k3.z + q3.w * k3.w;
            float dp = r0.x * p0.x + r0.y * p0.y + r0.z * p0.z + r0.w * p0.w
                     + r1.x * p1.x + r1.y * p1.y + r1.z * p1.z + r1.w * p1.w
                     + r2.x * p2.x + r2.y * p2.y + r2.z * p2.z + r2.w * p2.w;
            qk *= s1;
            float pt = -0.5f * hwv * (sqq_s[i] + sqk - 2.f * dp);
            float g = dm_s[i] * sm;
            size_t idx = rowbase + (size_t)i * LS + j;
            asd_out[idx] = qk * g;
            apts_out[idx] = pt * g;
            float logit = qk + pt + 1.0e9f * (g - 1.0f);
            sreg[i][jc] = logit;
            mx[i] = fmaxf(mx[i], logit);
        }
    }

    const int lane = t & 63, wid = t >> 6;
#pragma unroll
    for (int i = 0; i < 4; ++i) {
        float v = mx[i];
        for (int off = 32; off > 0; off >>= 1) v = fmaxf(v, __shfl_xor(v, off));
        if (lane == 0) red[wid][i] = v;
    }
    __syncthreads();
    float M[4], sum[4] = {0.f, 0.f, 0.f, 0.f};
#pragma unroll
    for (int i = 0; i < 4; ++i)
        M[i] = fmaxf(fmaxf(red[0][i], red[1][i]), fmaxf(red[2][i], red[3][i]));
    __syncthreads();  // everyone done reading red before reuse

#pragma unroll
    for (int jc = 0; jc < 8; ++jc) {
#pragma unroll
        for (int i = 0; i < 4; ++i) {
            float e = __expf(sreg[i][jc] - M[i]);
            sreg[i][jc] = e;
            sum[i] += e;
        }
    }
#pragma unroll
    for (int i = 0; i < 4; ++i) {
        float v = sum[i];
        for (int off = 32; off > 0; off >>= 1) v += __shfl_xor(v, off);
        if (lane == 0) red[wid][i] = v;
    }
    __syncthreads();
    float inv[4];
#pragma unroll
    for (int i = 0; i < 4; ++i)
        inv[i] = 1.0f / (red[0][i] + red[1][i] + red[2][i] + red[3][i]);

#pragma unroll
    for (int jc = 0; jc < 8; ++jc) {
        const int j = jc * 256 + t;
#pragma unroll
        for (int i = 0; i < 4; ++i)
            a_out[rowbase + (size_t)i * LS + j] = sreg[i][jc] * inv[i];
    }
}

// ---------------------------------------------------------------------------
// AV: o[i,h,c16] = sum_j a[h,i,j] v[j,h,c]; o_pt[i,h,pv,ax] likewise (24 cols).
// Block = 8 dst rows x one head, 320 threads: thread = (i_loc, c4 in 0..9,
// ks in 0..3 K-split). LDS reduction over ks (no atomics).
// ---------------------------------------------------------------------------
__global__ __launch_bounds__(320) void av_kernel(
    const float* __restrict__ a, const float* __restrict__ kvb,
    const float* __restrict__ vpb, float* __restrict__ o_buf,
    float* __restrict__ opt_buf)
{
    const int h = blockIdx.y;
    const int t = threadIdx.x;
    const int il = t / 40;
    const int s = t % 40;
    const int c4 = s % 10, ks = s / 10;
    const int i = blockIdx.x * 8 + il;
    const int c = c4 * 4;

    __shared__ float red[8][10][4][4];

    const float* arow = a + ((size_t)h * LD + i) * LS;
    const float* bp;
    size_t stride;
    if (c < 16) { bp = kvb + h * 32 + 16 + c; stride = 2 * NH * CH; }
    else        { bp = vpb + h * 24 + (c - 16); stride = NH * PV * 3; }

    float ax = 0.f, ay = 0.f, az = 0.f, aw = 0.f;
    const int kbeg = ks * 512;
    for (int k = kbeg; k < kbeg + 512; k += 4) {
        float4 av = *(const float4*)(arow + k);
        float4 b0 = *(const float4*)(bp + (size_t)(k + 0) * stride);
        float4 b1 = *(const float4*)(bp + (size_t)(k + 1) * stride);
        float4 b2 = *(const float4*)(bp + (size_t)(k + 2) * stride);
        float4 b3 = *(const float4*)(bp + (size_t)(k + 3) * stride);
        ax += av.x * b0.x + av.y * b1.x + av.z * b2.x + av.w * b3.x;
        ay += av.x * b0.y + av.y * b1.y + av.z * b2.y + av.w * b3.y;
        az += av.x * b0.z + av.y * b1.z + av.z * b2.z + av.w * b3.z;
        aw += av.x * b0.w + av.y * b1.w + av.z * b2.w + av.w * b3.w;
    }
    red[il][c4][ks][0] = ax;
    red[il][c4][ks][1] = ay;
    red[il][c4][ks][2] = az;
    red[il][c4][ks][3] = aw;
    __syncthreads();
    if (ks == 0) {
        float o0 = red[il][c4][0][0] + red[il][c4][1][0] + red[il][c4][2][0] + red[il][c4][3][0];
        float o1 = red[il][c4][0][1] + red[il][c4][1][1] + red[il][c4][2][1] + red[il][c4][3][1];
        float o2 = red[il][c4][0][2] + red[il][c4][1][2] + red[il][c4][2][2] + red[il][c4][3][2];
        float o3 = red[il][c4][0][3] + red[il][c4][1][3] + red[il][c4][2][3] + red[il][c4][3][3];
        float* dst;
        if (c < 16) dst = o_buf + i * (NH * CH) + h * CH + c;
        else        dst = opt_buf + i * (NH * PV * 3) + h * 24 + (c - 16);
        dst[0] = o0; dst[1] = o1; dst[2] = o2; dst[3] = o3;
    }
}

// ---------------------------------------------------------------------------
// Finalize: cat = [o(192) | x(96) | y(96) | z(96) | norm(96)]
// o_pt' = R_dst^T (o_pt - t_dst); norm = sqrt(|o_pt'|^2 + 1e-8)
// ---------------------------------------------------------------------------
__global__ __launch_bounds__(192) void finalize_kernel(
    const float* __restrict__ o_buf, const float* __restrict__ opt_buf,
    const float* __restrict__ Rd, const float* __restrict__ td,
    float* __restrict__ cat)
{
    const int i = blockIdx.x, t = threadIdx.x;
    cat[i * 576 + t] = o_buf[i * 192 + t];
    if (t < 96) {
        const float* op = opt_buf + i * 288 + t * 3;
        float x = op[0] - td[i * 3 + 0];
        float y = op[1] - td[i * 3 + 1];
        float z = op[2] - td[i * 3 + 2];
        const float* R = Rd + i * 9;
        float rx = R[0] * x + R[3] * y + R[6] * z;
        float ry = R[1] * x + R[4] * y + R[7] * z;
        float rz = R[2] * x + R[5] * y + R[8] * z;
        float* cc = cat + i * 576 + 192;
        cc[t] = rx;
        cc[96 + t] = ry;
        cc[192 + t] = rz;
        cc[288 + t] = sqrtf(rx * rx + ry * ry + rz * rz + 1e-8f);
    }
}

// ---------------------------------------------------------------------------
extern "C" void kernel_launch(void* const* d_in, const int* in_sizes, int n_in,
                              void* d_out, int out_size, void* d_ws, size_t ws_size,
                              hipStream_t stream)
{
    (void)in_sizes; (void)n_in; (void)out_size; (void)ws_size;
    const float* s_dst    = (const float*)d_in[0];
    const float* s_src    = (const float*)d_in[1];
    const float* R_dst    = (const float*)d_in[2];
    const float* t_dst    = (const float*)d_in[3];
    const float* R_src    = (const float*)d_in[4];
    const float* t_src    = (const float*)d_in[5];
    const float* dst_mask = (const float*)d_in[6];
    const float* src_mask = (const float*)d_in[7];
    const float* W_q      = (const float*)d_in[8];
    const float* W_kv     = (const float*)d_in[9];
    const float* W_qp     = (const float*)d_in[10];
    const float* W_kvp    = (const float*)d_in[11];
    const float* W_out    = (const float*)d_in[12];
    const float* b_out    = (const float*)d_in[13];
    const float* head_w   = (const float*)d_in[14];

    float* ws = (float*)d_ws;
    float* q_buf   = ws;                    // 512*192
    float* kv_buf  = q_buf   + 98304;       // 2048*384
    float* qp_raw  = kv_buf  + 786432;      // 512*144
    float* kvp_raw = qp_raw  + 73728;       // 2048*432
    float* qp_rot  = kvp_raw + 884736;      // 512*144
    float* sq_q    = qp_rot  + 73728;       // 512*12
    float* kp_buf  = sq_q    + 6144;        // 2048*144
    float* vp_buf  = kp_buf  + 294912;      // 2048*288
    float* sq_k    = vp_buf  + 589824;      // 2048*12
    float* o_buf   = sq_k    + 24576;       // 512*192
    float* opt_buf = o_buf   + 98304;       // 512*288
    float* cat_buf = opt_buf + 147456;      // 512*576

    float* out_s    = (float*)d_out;              // 512*384
    float* out_a    = out_s    + 196608;          // 12*512*2048
    float* out_asd  = out_a    + 12582912;
    float* out_apts = out_asd  + 12582912;

    dim3 b256(256);
    // Projections
    sgemm_kernel<<<dim3(3, 8),  b256, 0, stream>>>(s_dst, W_q,   nullptr, q_buf,   LD, 192, CS);
    sgemm_kernel<<<dim3(3, 8),  b256, 0, stream>>>(s_dst, W_qp,  nullptr, qp_raw,  LD, 144, CS);
    sgemm_kernel<<<dim3(6, 32), b256, 0, stream>>>(s_src, W_kv,  nullptr, kv_buf,  LS, 384, CS);
    sgemm_kernel<<<dim3(7, 32), b256, 0, stream>>>(s_src, W_kvp, nullptr, kvp_raw, LS, 432, CS);
    // Rotations + squared norms
    rot_dst_kernel<<<LD, 64, 0, stream>>>(qp_raw, R_dst, t_dst, qp_rot, sq_q);
    rot_src_kernel<<<LS, 192, 0, stream>>>(kvp_raw, R_src, t_src, kp_buf, vp_buf, sq_k);
    // Scores + softmax (+ a_sd, a_pts, a outputs)
    score_softmax_kernel<<<dim3(LD / 4, NH), b256, 0, stream>>>(
        q_buf, kv_buf, qp_rot, kp_buf, sq_q, sq_k, dst_mask, src_mask, head_w,
        out_a, out_asd, out_apts);
    // Attention-weighted values
    av_kernel<<<dim3(LD / 8, NH), 320, 0, stream>>>(out_a, kv_buf, vp_buf, o_buf, opt_buf);
    // Inverse rotation, norms, concat
    finalize_kernel<<<LD, 192, 0, stream>>>(o_buf, opt_buf, R_dst, t_dst, cat_buf);
    // Output projection
    sgemm_kernel<<<dim3(6, 8), b256, 0, stream>>>(cat_buf, W_out, b_out, out_s, LD, CS, 576);
}

// Round 2
// 538.860 us; speedup vs baseline: 1.0364x; 1.0364x over previous
//
#include <hip/hip_runtime.h>
#include <hip/hip_bf16.h>

// Problem constants
#define LD 512
#define LS 2048
#define CS 384
#define CH 16
#define NH 12
#define PQ 4
#define PV 8

// ---------------------------------------------------------------------------
// Generic fp32 SGEMM: C[M,N] = A[M,K] @ B[K,N] (+ bias). Row-major.
// BM=BN=64, BK=16, 256 threads, 4x4 micro-tile. M multiple of 64, K multiple
// of 16, N multiple of 4 (partial last N-tile guarded).
// ---------------------------------------------------------------------------
__global__ __launch_bounds__(256) void sgemm_kernel(
    const float* __restrict__ A, const float* __restrict__ B,
    const float* __restrict__ bias, float* __restrict__ C,
    int M, int N, int K)
{
    __shared__ float As[16][68];
    __shared__ float Bs[16][68];
    const int t = threadIdx.x;
    const int tx = t & 15, ty = t >> 4;
    const int m0 = blockIdx.y * 64, n0 = blockIdx.x * 64;

    float acc[4][4];
#pragma unroll
    for (int i = 0; i < 4; ++i)
#pragma unroll
        for (int j = 0; j < 4; ++j) acc[i][j] = 0.f;

    for (int k0 = 0; k0 < K; k0 += 16) {
        {
            int r = t >> 2;
            int kk = (t & 3) * 4;
            const float* ap = A + (size_t)(m0 + r) * K + k0 + kk;
            float4 a4 = *(const float4*)ap;
            As[kk + 0][r] = a4.x;
            As[kk + 1][r] = a4.y;
            As[kk + 2][r] = a4.z;
            As[kk + 3][r] = a4.w;
        }
        {
            int kk = t >> 4;
            int nn = (t & 15) * 4;
            int n = n0 + nn;
            float4 b4 = make_float4(0.f, 0.f, 0.f, 0.f);
            if (n < N) b4 = *(const float4*)(B + (size_t)(k0 + kk) * N + n);
            Bs[kk][nn + 0] = b4.x;
            Bs[kk][nn + 1] = b4.y;
            Bs[kk][nn + 2] = b4.z;
            Bs[kk][nn + 3] = b4.w;
        }
        __syncthreads();
#pragma unroll
        for (int kk = 0; kk < 16; ++kk) {
            float4 a4 = *(const float4*)&As[kk][ty * 4];
            float4 b4 = *(const float4*)&Bs[kk][tx * 4];
            acc[0][0] += a4.x * b4.x; acc[0][1] += a4.x * b4.y; acc[0][2] += a4.x * b4.z; acc[0][3] += a4.x * b4.w;
            acc[1][0] += a4.y * b4.x; acc[1][1] += a4.y * b4.y; acc[1][2] += a4.y * b4.z; acc[1][3] += a4.y * b4.w;
            acc[2][0] += a4.z * b4.x; acc[2][1] += a4.z * b4.y; acc[2][2] += a4.z * b4.z; acc[2][3] += a4.z * b4.w;
            acc[3][0] += a4.w * b4.x; acc[3][1] += a4.w * b4.y; acc[3][2] += a4.w * b4.z; acc[3][3] += a4.w * b4.w;
        }
        __syncthreads();
    }
#pragma unroll
    for (int ii = 0; ii < 4; ++ii) {
        int row = m0 + ty * 4 + ii;
#pragma unroll
        for (int jj = 0; jj < 4; ++jj) {
            int n = n0 + tx * 4 + jj;
            if (n < N) {
                float v = acc[ii][jj];
                if (bias) v += bias[n];
                C[(size_t)row * N + n] = v;
            }
        }
    }
}

// ---------------------------------------------------------------------------
// Rotate dst query points: qp_rot = R_dst @ qp_raw + t_dst ; sq_q = sum |qp|^2
// ---------------------------------------------------------------------------
__global__ __launch_bounds__(64) void rot_dst_kernel(
    const float* __restrict__ qp_raw, const float* __restrict__ Rd,
    const float* __restrict__ td, float* __restrict__ qp_rot,
    float* __restrict__ sqq)
{
    const int i = blockIdx.x, t = threadIdx.x;
    __shared__ float part[48];
    if (t < 48) {
        float x = qp_raw[i * 144 + t];
        float y = qp_raw[i * 144 + 48 + t];
        float z = qp_raw[i * 144 + 96 + t];
        const float* R = Rd + i * 9;
        float rx = R[0] * x + R[1] * y + R[2] * z + td[i * 3 + 0];
        float ry = R[3] * x + R[4] * y + R[5] * z + td[i * 3 + 1];
        float rz = R[6] * x + R[7] * y + R[8] * z + td[i * 3 + 2];
        qp_rot[i * 144 + t * 3 + 0] = rx;
        qp_rot[i * 144 + t * 3 + 1] = ry;
        qp_rot[i * 144 + t * 3 + 2] = rz;
        part[t] = rx * rx + ry * ry + rz * rz;
    }
    __syncthreads();
    if (t < NH) sqq[i * NH + t] = part[t * 4] + part[t * 4 + 1] + part[t * 4 + 2] + part[t * 4 + 3];
}

// ---------------------------------------------------------------------------
// Rotate src points. Writes TRANSPOSED layouts:
//   kpT[h*12 + pq*3+ax][j], vAllT[h*40 + 16 + pv*3+ax][j], sqkT[h][j]
// ---------------------------------------------------------------------------
__global__ __launch_bounds__(192) void rot_src_kernel(
    const float* __restrict__ kvp_raw, const float* __restrict__ Rs,
    const float* __restrict__ ts, float* __restrict__ kpT,
    float* __restrict__ vAllT, float* __restrict__ sqkT)
{
    const int j = blockIdx.x, t = threadIdx.x;
    __shared__ float part[48];
    if (t < 144) {
        float x = kvp_raw[j * 432 + t];
        float y = kvp_raw[j * 432 + 144 + t];
        float z = kvp_raw[j * 432 + 288 + t];
        const float* R = Rs + j * 9;
        float rx = R[0] * x + R[1] * y + R[2] * z + ts[j * 3 + 0];
        float ry = R[3] * x + R[4] * y + R[5] * z + ts[j * 3 + 1];
        float rz = R[6] * x + R[7] * y + R[8] * z + ts[j * 3 + 2];
        int h = t / 12, pp = t % 12;
        if (pp < 4) {
            size_t o = ((size_t)h * 12 + pp * 3) * LS + j;
            kpT[o] = rx; kpT[o + LS] = ry; kpT[o + 2 * LS] = rz;
            part[h * 4 + pp] = rx * rx + ry * ry + rz * rz;
        } else {
            size_t o = ((size_t)h * 40 + 16 + (pp - 4) * 3) * LS + j;
            vAllT[o] = rx; vAllT[o + LS] = ry; vAllT[o + 2 * LS] = rz;
        }
    }
    __syncthreads();
    if (t < NH) sqkT[(size_t)t * LS + j] = part[t * 4] + part[t * 4 + 1] + part[t * 4 + 2] + part[t * 4 + 3];
}

// ---------------------------------------------------------------------------
// Transpose kv_buf[j][h*32 + c] -> kT[h*16+c][j] (c<16) / vAllT[h*40+c-16][j]
// Block: one head x 64 j. LDS tile with +1 pad.
// ---------------------------------------------------------------------------
__global__ __launch_bounds__(256) void transpose_kv_kernel(
    const float* __restrict__ kvb, float* __restrict__ kT,
    float* __restrict__ vAllT)
{
    const int h = blockIdx.y, j0 = blockIdx.x * 64, t = threadIdx.x;
    __shared__ float tile[64][33];
#pragma unroll
    for (int r = 0; r < 2; ++r) {
        int f = t + r * 256;
        int jl = f >> 3, c4 = (f & 7) * 4;
        float4 v = *(const float4*)(kvb + (size_t)(j0 + jl) * (2 * NH * CH) + h * 32 + c4);
        tile[jl][c4 + 0] = v.x;
        tile[jl][c4 + 1] = v.y;
        tile[jl][c4 + 2] = v.z;
        tile[jl][c4 + 3] = v.w;
    }
    __syncthreads();
    const int jl = t & 63, cr = t >> 6;
#pragma unroll
    for (int cg = 0; cg < 8; ++cg) {
        int c = cg * 4 + cr;
        float v = tile[jl][c];
        if (c < 16) kT[((size_t)h * 16 + c) * LS + j0 + jl] = v;
        else        vAllT[((size_t)h * 40 + (c - 16)) * LS + j0 + jl] = v;
    }
}

// ---------------------------------------------------------------------------
// Scores + softmax, coalesced. Block = (4 dst rows) x head, 256 threads.
// Thread owns 2 j-quads (float4 along j). Q-side read via uniform (scalar)
// global loads. Writes a, a_sd, a_pts.
// ---------------------------------------------------------------------------
__global__ __launch_bounds__(256) void score_softmax_kernel(
    const float* __restrict__ qb, const float* __restrict__ kT,
    const float* __restrict__ qpb, const float* __restrict__ kpT,
    const float* __restrict__ sqq_g, const float* __restrict__ sqkT,
    const float* __restrict__ dmask, const float* __restrict__ smask,
    const float* __restrict__ head_w,
    float* __restrict__ a_out, float* __restrict__ asd_out,
    float* __restrict__ apts_out)
{
    const int h = blockIdx.y;
    const int i0 = blockIdx.x * 4;
    const int t = threadIdx.x;
    __shared__ float red[4][4];

    const float hwv = log1pf(__expf(head_w[h])) * (1.0f / 6.0f);
    const float s1 = 0.17677669529663687f;  // sqrt(1/32)
    const size_t rowbase = ((size_t)h * LD + i0) * LS;

    float4 sregv[4][2];
    float mx[4] = {-3.0e38f, -3.0e38f, -3.0e38f, -3.0e38f};

#pragma unroll
    for (int jc = 0; jc < 2; ++jc) {
        const int j = (jc * 256 + t) * 4;
        float4 sm4 = *(const float4*)(smask + j);
        float4 sqk4 = *(const float4*)(sqkT + (size_t)h * LS + j);
        float4 qk4[4], dp4[4];
#pragma unroll
        for (int i = 0; i < 4; ++i) {
            qk4[i] = make_float4(0.f, 0.f, 0.f, 0.f);
            dp4[i] = make_float4(0.f, 0.f, 0.f, 0.f);
        }
#pragma unroll
        for (int c = 0; c < 16; ++c) {
            float4 k4 = *(const float4*)(kT + ((size_t)h * 16 + c) * LS + j);
#pragma unroll
            for (int i = 0; i < 4; ++i) {
                float qv = qb[(size_t)(i0 + i) * (NH * CH) + h * CH + c];
                qk4[i].x += qv * k4.x; qk4[i].y += qv * k4.y;
                qk4[i].z += qv * k4.z; qk4[i].w += qv * k4.w;
            }
        }
#pragma unroll
        for (int d = 0; d < 12; ++d) {
            float4 p4 = *(const float4*)(kpT + ((size_t)h * 12 + d) * LS + j);
#pragma unroll
            for (int i = 0; i < 4; ++i) {
                float rv = qpb[(size_t)(i0 + i) * 144 + h * 12 + d];
                dp4[i].x += rv * p4.x; dp4[i].y += rv * p4.y;
                dp4[i].z += rv * p4.z; dp4[i].w += rv * p4.w;
            }
        }
#pragma unroll
        for (int i = 0; i < 4; ++i) {
            float sqq = sqq_g[(size_t)(i0 + i) * NH + h];
            float dm = dmask[i0 + i];
            float4 qk, pt, g, logit;
            qk.x = qk4[i].x * s1; qk.y = qk4[i].y * s1;
            qk.z = qk4[i].z * s1; qk.w = qk4[i].w * s1;
            pt.x = -0.5f * hwv * (sqq + sqk4.x - 2.f * dp4[i].x);
            pt.y = -0.5f * hwv * (sqq + sqk4.y - 2.f * dp4[i].y);
            pt.z = -0.5f * hwv * (sqq + sqk4.z - 2.f * dp4[i].z);
            pt.w = -0.5f * hwv * (sqq + sqk4.w - 2.f * dp4[i].w);
            g.x = dm * sm4.x; g.y = dm * sm4.y; g.z = dm * sm4.z; g.w = dm * sm4.w;
            size_t idx = rowbase + (size_t)i * LS + j;
            float4 asd = make_float4(qk.x * g.x, qk.y * g.y, qk.z * g.z, qk.w * g.w);
            float4 apts = make_float4(pt.x * g.x, pt.y * g.y, pt.z * g.z, pt.w * g.w);
            *(float4*)(asd_out + idx) = asd;
            *(float4*)(apts_out + idx) = apts;
            logit.x = qk.x + pt.x + 1.0e9f * (g.x - 1.0f);
            logit.y = qk.y + pt.y + 1.0e9f * (g.y - 1.0f);
            logit.z = qk.z + pt.z + 1.0e9f * (g.z - 1.0f);
            logit.w = qk.w + pt.w + 1.0e9f * (g.w - 1.0f);
            sregv[i][jc] = logit;
            mx[i] = fmaxf(mx[i], fmaxf(fmaxf(logit.x, logit.y), fmaxf(logit.z, logit.w)));
        }
    }

    const int lane = t & 63, wid = t >> 6;
#pragma unroll
    for (int i = 0; i < 4; ++i) {
        float v = mx[i];
        for (int off = 32; off > 0; off >>= 1) v = fmaxf(v, __shfl_xor(v, off));
        if (lane == 0) red[wid][i] = v;
    }
    __syncthreads();
    float M[4], sum[4] = {0.f, 0.f, 0.f, 0.f};
#pragma unroll
    for (int i = 0; i < 4; ++i)
        M[i] = fmaxf(fmaxf(red[0][i], red[1][i]), fmaxf(red[2][i], red[3][i]));
    __syncthreads();

#pragma unroll
    for (int jc = 0; jc < 2; ++jc) {
#pragma unroll
        for (int i = 0; i < 4; ++i) {
            float4 e;
            e.x = __expf(sregv[i][jc].x - M[i]);
            e.y = __expf(sregv[i][jc].y - M[i]);
            e.z = __expf(sregv[i][jc].z - M[i]);
            e.w = __expf(sregv[i][jc].w - M[i]);
            sregv[i][jc] = e;
            sum[i] += e.x + e.y + e.z + e.w;
        }
    }
#pragma unroll
    for (int i = 0; i < 4; ++i) {
        float v = sum[i];
        for (int off = 32; off > 0; off >>= 1) v += __shfl_xor(v, off);
        if (lane == 0) red[wid][i] = v;
    }
    __syncthreads();
    float inv[4];
#pragma unroll
    for (int i = 0; i < 4; ++i)
        inv[i] = 1.0f / (red[0][i] + red[1][i] + red[2][i] + red[3][i]);

#pragma unroll
    for (int jc = 0; jc < 2; ++jc) {
        const int j = (jc * 256 + t) * 4;
#pragma unroll
        for (int i = 0; i < 4; ++i) {
            float4 e = sregv[i][jc];
            float4 o = make_float4(e.x * inv[i], e.y * inv[i], e.z * inv[i], e.w * inv[i]);
            *(float4*)(a_out + rowbase + (size_t)i * LS + j) = o;
        }
    }
}

// ---------------------------------------------------------------------------
// AV with transposed V: block = (8 dst rows x head), 1024 threads = 16 waves.
// Wave w: i_loc = w>>1, c-half = w&1 (20 of 40 channels). Lanes split j;
// float4 dot streams + butterfly shuffle reduction.
// ---------------------------------------------------------------------------
__global__ __launch_bounds__(1024) void av_kernel(
    const float* __restrict__ a, const float* __restrict__ vAllT,
    float* __restrict__ o_buf, float* __restrict__ opt_buf)
{
    const int h = blockIdx.y, t = threadIdx.x;
    const int w = t >> 6, lane = t & 63;
    const int il = w >> 1, chalf = w & 1;
    const int i = blockIdx.x * 8 + il;

    const float* arow = a + ((size_t)h * LD + i) * LS;
    const float* vbase = vAllT + ((size_t)h * 40 + chalf * 20) * LS;

    float4 acc[20];
#pragma unroll
    for (int cc = 0; cc < 20; ++cc) acc[cc] = make_float4(0.f, 0.f, 0.f, 0.f);

    for (int jt = 0; jt < 8; ++jt) {
        const int j = jt * 256 + lane * 4;
        float4 a4 = *(const float4*)(arow + j);
#pragma unroll
        for (int cc = 0; cc < 20; ++cc) {
            float4 v4 = *(const float4*)(vbase + (size_t)cc * LS + j);
            acc[cc].x += a4.x * v4.x;
            acc[cc].y += a4.y * v4.y;
            acc[cc].z += a4.z * v4.z;
            acc[cc].w += a4.w * v4.w;
        }
    }
#pragma unroll
    for (int cc = 0; cc < 20; ++cc) {
        float s = acc[cc].x + acc[cc].y + acc[cc].z + acc[cc].w;
        for (int off = 32; off > 0; off >>= 1) s += __shfl_xor(s, off);
        if (lane == 0) {
            int ch = chalf * 20 + cc;
            if (ch < 16) o_buf[(size_t)i * (NH * CH) + h * CH + ch] = s;
            else         opt_buf[(size_t)i * (NH * PV * 3) + h * 24 + (ch - 16)] = s;
        }
    }
}

// ---------------------------------------------------------------------------
// Finalize: cat = [o(192) | x(96) | y(96) | z(96) | norm(96)]
// ---------------------------------------------------------------------------
__global__ __launch_bounds__(192) void finalize_kernel(
    const float* __restrict__ o_buf, const float* __restrict__ opt_buf,
    const float* __restrict__ Rd, const float* __restrict__ td,
    float* __restrict__ cat)
{
    const int i = blockIdx.x, t = threadIdx.x;
    cat[i * 576 + t] = o_buf[i * 192 + t];
    if (t < 96) {
        const float* op = opt_buf + i * 288 + t * 3;
        float x = op[0] - td[i * 3 + 0];
        float y = op[1] - td[i * 3 + 1];
        float z = op[2] - td[i * 3 + 2];
        const float* R = Rd + i * 9;
        float rx = R[0] * x + R[3] * y + R[6] * z;
        float ry = R[1] * x + R[4] * y + R[7] * z;
        float rz = R[2] * x + R[5] * y + R[8] * z;
        float* cc = cat + i * 576 + 192;
        cc[t] = rx;
        cc[96 + t] = ry;
        cc[192 + t] = rz;
        cc[288 + t] = sqrtf(rx * rx + ry * ry + rz * rz + 1e-8f);
    }
}

// ---------------------------------------------------------------------------
extern "C" void kernel_launch(void* const* d_in, const int* in_sizes, int n_in,
                              void* d_out, int out_size, void* d_ws, size_t ws_size,
                              hipStream_t stream)
{
    (void)in_sizes; (void)n_in; (void)out_size; (void)ws_size;
    const float* s_dst    = (const float*)d_in[0];
    const float* s_src    = (const float*)d_in[1];
    const float* R_dst    = (const float*)d_in[2];
    const float* t_dst    = (const float*)d_in[3];
    const float* R_src    = (const float*)d_in[4];
    const float* t_src    = (const float*)d_in[5];
    const float* dst_mask = (const float*)d_in[6];
    const float* src_mask = (const float*)d_in[7];
    const float* W_q      = (const float*)d_in[8];
    const float* W_kv     = (const float*)d_in[9];
    const float* W_qp     = (const float*)d_in[10];
    const float* W_kvp    = (const float*)d_in[11];
    const float* W_out    = (const float*)d_in[12];
    const float* b_out    = (const float*)d_in[13];
    const float* head_w   = (const float*)d_in[14];

    float* ws = (float*)d_ws;
    float* q_buf   = ws;                    // 512*192   = 98304
    float* kv_buf  = q_buf   + 98304;       // 2048*384  = 786432
    float* qp_raw  = kv_buf  + 786432;      // 512*144   = 73728
    float* kvp_raw = qp_raw  + 73728;       // 2048*432  = 884736
    float* qp_rot  = kvp_raw + 884736;      // 512*144   = 73728
    float* sq_q    = qp_rot  + 73728;       // 512*12    = 6144
    float* o_buf   = sq_q    + 6144;        // 512*192   = 98304
    float* opt_buf = o_buf   + 98304;       // 512*288   = 147456
    float* cat_buf = opt_buf + 147456;      // 512*576   = 294912
    float* kT      = cat_buf + 294912;      // 12*16*2048 = 393216
    float* vAllT   = kT      + 393216;      // 12*40*2048 = 983040
    float* kpT     = vAllT   + 983040;      // 12*12*2048 = 294912
    float* sqkT    = kpT     + 294912;      // 12*2048    = 24576

    float* out_s    = (float*)d_out;              // 512*384
    float* out_a    = out_s    + 196608;          // 12*512*2048
    float* out_asd  = out_a    + 12582912;
    float* out_apts = out_asd  + 12582912;

    dim3 b256(256);
    // Projections
    sgemm_kernel<<<dim3(3, 8),  b256, 0, stream>>>(s_dst, W_q,   nullptr, q_buf,   LD, 192, CS);
    sgemm_kernel<<<dim3(3, 8),  b256, 0, stream>>>(s_dst, W_qp,  nullptr, qp_raw,  LD, 144, CS);
    sgemm_kernel<<<dim3(6, 32), b256, 0, stream>>>(s_src, W_kv,  nullptr, kv_buf,  LS, 384, CS);
    sgemm_kernel<<<dim3(7, 32), b256, 0, stream>>>(s_src, W_kvp, nullptr, kvp_raw, LS, 432, CS);
    // Rotations + squared norms (src writes transposed) + kv transpose
    rot_dst_kernel<<<LD, 64, 0, stream>>>(qp_raw, R_dst, t_dst, qp_rot, sq_q);
    rot_src_kernel<<<LS, 192, 0, stream>>>(kvp_raw, R_src, t_src, kpT, vAllT, sqkT);
    transpose_kv_kernel<<<dim3(32, 12), b256, 0, stream>>>(kv_buf, kT, vAllT);
    // Scores + softmax (+ a_sd, a_pts, a outputs)
    score_softmax_kernel<<<dim3(LD / 4, NH), b256, 0, stream>>>(
        q_buf, kT, qp_rot, kpT, sq_q, sqkT, dst_mask, src_mask, head_w,
        out_a, out_asd, out_apts);
    // Attention-weighted values
    av_kernel<<<dim3(LD / 8, NH), dim3(1024), 0, stream>>>(out_a, vAllT, o_buf, opt_buf);
    // Inverse rotation, norms, concat
    finalize_kernel<<<LD, 192, 0, stream>>>(o_buf, opt_buf, R_dst, t_dst, cat_buf);
    // Output projection
    sgemm_kernel<<<dim3(6, 8), b256, 0, stream>>>(cat_buf, W_out, b_out, out_s, LD, CS, 576);
}

// Round 3
// 434.849 us; speedup vs baseline: 1.2843x; 1.2392x over previous
//
#include <hip/hip_runtime.h>
#include <hip/hip_bf16.h>

// Problem constants
#define LD 512
#define LS 2048
#define CS 384
#define CH 16
#define NH 12
#define PQ 4
#define PV 8

typedef __bf16 bf16x8 __attribute__((ext_vector_type(8)));
typedef float  f32x4  __attribute__((ext_vector_type(4)));

// ---------------------------------------------------------------------------
// Generic fp32 SGEMM: C[M,N] = A[M,K] @ B[K,N] (+ bias). Row-major.
// ---------------------------------------------------------------------------
__global__ __launch_bounds__(256) void sgemm_kernel(
    const float* __restrict__ A, const float* __restrict__ B,
    const float* __restrict__ bias, float* __restrict__ C,
    int M, int N, int K)
{
    __shared__ float As[16][68];
    __shared__ float Bs[16][68];
    const int t = threadIdx.x;
    const int tx = t & 15, ty = t >> 4;
    const int m0 = blockIdx.y * 64, n0 = blockIdx.x * 64;

    float acc[4][4];
#pragma unroll
    for (int i = 0; i < 4; ++i)
#pragma unroll
        for (int j = 0; j < 4; ++j) acc[i][j] = 0.f;

    for (int k0 = 0; k0 < K; k0 += 16) {
        {
            int r = t >> 2;
            int kk = (t & 3) * 4;
            const float* ap = A + (size_t)(m0 + r) * K + k0 + kk;
            float4 a4 = *(const float4*)ap;
            As[kk + 0][r] = a4.x;
            As[kk + 1][r] = a4.y;
            As[kk + 2][r] = a4.z;
            As[kk + 3][r] = a4.w;
        }
        {
            int kk = t >> 4;
            int nn = (t & 15) * 4;
            int n = n0 + nn;
            float4 b4 = make_float4(0.f, 0.f, 0.f, 0.f);
            if (n < N) b4 = *(const float4*)(B + (size_t)(k0 + kk) * N + n);
            Bs[kk][nn + 0] = b4.x;
            Bs[kk][nn + 1] = b4.y;
            Bs[kk][nn + 2] = b4.z;
            Bs[kk][nn + 3] = b4.w;
        }
        __syncthreads();
#pragma unroll
        for (int kk = 0; kk < 16; ++kk) {
            float4 a4 = *(const float4*)&As[kk][ty * 4];
            float4 b4 = *(const float4*)&Bs[kk][tx * 4];
            acc[0][0] += a4.x * b4.x; acc[0][1] += a4.x * b4.y; acc[0][2] += a4.x * b4.z; acc[0][3] += a4.x * b4.w;
            acc[1][0] += a4.y * b4.x; acc[1][1] += a4.y * b4.y; acc[1][2] += a4.y * b4.z; acc[1][3] += a4.y * b4.w;
            acc[2][0] += a4.z * b4.x; acc[2][1] += a4.z * b4.y; acc[2][2] += a4.z * b4.z; acc[2][3] += a4.z * b4.w;
            acc[3][0] += a4.w * b4.x; acc[3][1] += a4.w * b4.y; acc[3][2] += a4.w * b4.z; acc[3][3] += a4.w * b4.w;
        }
        __syncthreads();
    }
#pragma unroll
    for (int ii = 0; ii < 4; ++ii) {
        int row = m0 + ty * 4 + ii;
#pragma unroll
        for (int jj = 0; jj < 4; ++jj) {
            int n = n0 + tx * 4 + jj;
            if (n < N) {
                float v = acc[ii][jj];
                if (bias) v += bias[n];
                C[(size_t)row * N + n] = v;
            }
        }
    }
}

// ---------------------------------------------------------------------------
// Rotate dst query points
// ---------------------------------------------------------------------------
__global__ __launch_bounds__(64) void rot_dst_kernel(
    const float* __restrict__ qp_raw, const float* __restrict__ Rd,
    const float* __restrict__ td, float* __restrict__ qp_rot,
    float* __restrict__ sqq)
{
    const int i = blockIdx.x, t = threadIdx.x;
    __shared__ float part[48];
    if (t < 48) {
        float x = qp_raw[i * 144 + t];
        float y = qp_raw[i * 144 + 48 + t];
        float z = qp_raw[i * 144 + 96 + t];
        const float* R = Rd + i * 9;
        float rx = R[0] * x + R[1] * y + R[2] * z + td[i * 3 + 0];
        float ry = R[3] * x + R[4] * y + R[5] * z + td[i * 3 + 1];
        float rz = R[6] * x + R[7] * y + R[8] * z + td[i * 3 + 2];
        qp_rot[i * 144 + t * 3 + 0] = rx;
        qp_rot[i * 144 + t * 3 + 1] = ry;
        qp_rot[i * 144 + t * 3 + 2] = rz;
        part[t] = rx * rx + ry * ry + rz * rz;
    }
    __syncthreads();
    if (t < NH) sqq[i * NH + t] = part[t * 4] + part[t * 4 + 1] + part[t * 4 + 2] + part[t * 4 + 3];
}

// ---------------------------------------------------------------------------
// Rotate src points. Writes TRANSPOSED layouts:
//   kpT[h*12 + pq*3+ax][j], vAllT[h*40 + 16 + pv*3+ax][j], sqkT[h][j]
// ---------------------------------------------------------------------------
__global__ __launch_bounds__(192) void rot_src_kernel(
    const float* __restrict__ kvp_raw, const float* __restrict__ Rs,
    const float* __restrict__ ts, float* __restrict__ kpT,
    float* __restrict__ vAllT, float* __restrict__ sqkT)
{
    const int j = blockIdx.x, t = threadIdx.x;
    __shared__ float part[48];
    if (t < 144) {
        float x = kvp_raw[j * 432 + t];
        float y = kvp_raw[j * 432 + 144 + t];
        float z = kvp_raw[j * 432 + 288 + t];
        const float* R = Rs + j * 9;
        float rx = R[0] * x + R[1] * y + R[2] * z + ts[j * 3 + 0];
        float ry = R[3] * x + R[4] * y + R[5] * z + ts[j * 3 + 1];
        float rz = R[6] * x + R[7] * y + R[8] * z + ts[j * 3 + 2];
        int h = t / 12, pp = t % 12;
        if (pp < 4) {
            size_t o = ((size_t)h * 12 + pp * 3) * LS + j;
            kpT[o] = rx; kpT[o + LS] = ry; kpT[o + 2 * LS] = rz;
            part[h * 4 + pp] = rx * rx + ry * ry + rz * rz;
        } else {
            size_t o = ((size_t)h * 40 + 16 + (pp - 4) * 3) * LS + j;
            vAllT[o] = rx; vAllT[o + LS] = ry; vAllT[o + 2 * LS] = rz;
        }
    }
    __syncthreads();
    if (t < NH) sqkT[(size_t)t * LS + j] = part[t * 4] + part[t * 4 + 1] + part[t * 4 + 2] + part[t * 4 + 3];
}

// ---------------------------------------------------------------------------
// Transpose kv_buf[j][h*32 + c] -> kT[h*16+c][j] (c<16) / vAllT[h*40+c-16][j]
// ---------------------------------------------------------------------------
__global__ __launch_bounds__(256) void transpose_kv_kernel(
    const float* __restrict__ kvb, float* __restrict__ kT,
    float* __restrict__ vAllT)
{
    const int h = blockIdx.y, j0 = blockIdx.x * 64, t = threadIdx.x;
    __shared__ float tile[64][33];
#pragma unroll
    for (int r = 0; r < 2; ++r) {
        int f = t + r * 256;
        int jl = f >> 3, c4 = (f & 7) * 4;
        float4 v = *(const float4*)(kvb + (size_t)(j0 + jl) * (2 * NH * CH) + h * 32 + c4);
        tile[jl][c4 + 0] = v.x;
        tile[jl][c4 + 1] = v.y;
        tile[jl][c4 + 2] = v.z;
        tile[jl][c4 + 3] = v.w;
    }
    __syncthreads();
    const int jl = t & 63, cr = t >> 6;
#pragma unroll
    for (int cg = 0; cg < 8; ++cg) {
        int c = cg * 4 + cr;
        float v = tile[jl][c];
        if (c < 16) kT[((size_t)h * 16 + c) * LS + j0 + jl] = v;
        else        vAllT[((size_t)h * 40 + (c - 16)) * LS + j0 + jl] = v;
    }
}

// ---------------------------------------------------------------------------
// Scores + softmax, coalesced. (unchanged from round 2)
// ---------------------------------------------------------------------------
__global__ __launch_bounds__(256) void score_softmax_kernel(
    const float* __restrict__ qb, const float* __restrict__ kT,
    const float* __restrict__ qpb, const float* __restrict__ kpT,
    const float* __restrict__ sqq_g, const float* __restrict__ sqkT,
    const float* __restrict__ dmask, const float* __restrict__ smask,
    const float* __restrict__ head_w,
    float* __restrict__ a_out, float* __restrict__ asd_out,
    float* __restrict__ apts_out)
{
    const int h = blockIdx.y;
    const int i0 = blockIdx.x * 4;
    const int t = threadIdx.x;
    __shared__ float red[4][4];

    const float hwv = log1pf(__expf(head_w[h])) * (1.0f / 6.0f);
    const float s1 = 0.17677669529663687f;  // sqrt(1/32)
    const size_t rowbase = ((size_t)h * LD + i0) * LS;

    float4 sregv[4][2];
    float mx[4] = {-3.0e38f, -3.0e38f, -3.0e38f, -3.0e38f};

#pragma unroll
    for (int jc = 0; jc < 2; ++jc) {
        const int j = (jc * 256 + t) * 4;
        float4 sm4 = *(const float4*)(smask + j);
        float4 sqk4 = *(const float4*)(sqkT + (size_t)h * LS + j);
        float4 qk4[4], dp4[4];
#pragma unroll
        for (int i = 0; i < 4; ++i) {
            qk4[i] = make_float4(0.f, 0.f, 0.f, 0.f);
            dp4[i] = make_float4(0.f, 0.f, 0.f, 0.f);
        }
#pragma unroll
        for (int c = 0; c < 16; ++c) {
            float4 k4 = *(const float4*)(kT + ((size_t)h * 16 + c) * LS + j);
#pragma unroll
            for (int i = 0; i < 4; ++i) {
                float qv = qb[(size_t)(i0 + i) * (NH * CH) + h * CH + c];
                qk4[i].x += qv * k4.x; qk4[i].y += qv * k4.y;
                qk4[i].z += qv * k4.z; qk4[i].w += qv * k4.w;
            }
        }
#pragma unroll
        for (int d = 0; d < 12; ++d) {
            float4 p4 = *(const float4*)(kpT + ((size_t)h * 12 + d) * LS + j);
#pragma unroll
            for (int i = 0; i < 4; ++i) {
                float rv = qpb[(size_t)(i0 + i) * 144 + h * 12 + d];
                dp4[i].x += rv * p4.x; dp4[i].y += rv * p4.y;
                dp4[i].z += rv * p4.z; dp4[i].w += rv * p4.w;
            }
        }
#pragma unroll
        for (int i = 0; i < 4; ++i) {
            float sqq = sqq_g[(size_t)(i0 + i) * NH + h];
            float dm = dmask[i0 + i];
            float4 qk, pt, g, logit;
            qk.x = qk4[i].x * s1; qk.y = qk4[i].y * s1;
            qk.z = qk4[i].z * s1; qk.w = qk4[i].w * s1;
            pt.x = -0.5f * hwv * (sqq + sqk4.x - 2.f * dp4[i].x);
            pt.y = -0.5f * hwv * (sqq + sqk4.y - 2.f * dp4[i].y);
            pt.z = -0.5f * hwv * (sqq + sqk4.z - 2.f * dp4[i].z);
            pt.w = -0.5f * hwv * (sqq + sqk4.w - 2.f * dp4[i].w);
            g.x = dm * sm4.x; g.y = dm * sm4.y; g.z = dm * sm4.z; g.w = dm * sm4.w;
            size_t idx = rowbase + (size_t)i * LS + j;
            float4 asd = make_float4(qk.x * g.x, qk.y * g.y, qk.z * g.z, qk.w * g.w);
            float4 apts = make_float4(pt.x * g.x, pt.y * g.y, pt.z * g.z, pt.w * g.w);
            *(float4*)(asd_out + idx) = asd;
            *(float4*)(apts_out + idx) = apts;
            logit.x = qk.x + pt.x + 1.0e9f * (g.x - 1.0f);
            logit.y = qk.y + pt.y + 1.0e9f * (g.y - 1.0f);
            logit.z = qk.z + pt.z + 1.0e9f * (g.z - 1.0f);
            logit.w = qk.w + pt.w + 1.0e9f * (g.w - 1.0f);
            sregv[i][jc] = logit;
            mx[i] = fmaxf(mx[i], fmaxf(fmaxf(logit.x, logit.y), fmaxf(logit.z, logit.w)));
        }
    }

    const int lane = t & 63, wid = t >> 6;
#pragma unroll
    for (int i = 0; i < 4; ++i) {
        float v = mx[i];
        for (int off = 32; off > 0; off >>= 1) v = fmaxf(v, __shfl_xor(v, off));
        if (lane == 0) red[wid][i] = v;
    }
    __syncthreads();
    float M[4], sum[4] = {0.f, 0.f, 0.f, 0.f};
#pragma unroll
    for (int i = 0; i < 4; ++i)
        M[i] = fmaxf(fmaxf(red[0][i], red[1][i]), fmaxf(red[2][i], red[3][i]));
    __syncthreads();

#pragma unroll
    for (int jc = 0; jc < 2; ++jc) {
#pragma unroll
        for (int i = 0; i < 4; ++i) {
            float4 e;
            e.x = __expf(sregv[i][jc].x - M[i]);
            e.y = __expf(sregv[i][jc].y - M[i]);
            e.z = __expf(sregv[i][jc].z - M[i]);
            e.w = __expf(sregv[i][jc].w - M[i]);
            sregv[i][jc] = e;
            sum[i] += e.x + e.y + e.z + e.w;
        }
    }
#pragma unroll
    for (int i = 0; i < 4; ++i) {
        float v = sum[i];
        for (int off = 32; off > 0; off >>= 1) v += __shfl_xor(v, off);
        if (lane == 0) red[wid][i] = v;
    }
    __syncthreads();
    float inv[4];
#pragma unroll
    for (int i = 0; i < 4; ++i)
        inv[i] = 1.0f / (red[0][i] + red[1][i] + red[2][i] + red[3][i]);

#pragma unroll
    for (int jc = 0; jc < 2; ++jc) {
        const int j = (jc * 256 + t) * 4;
#pragma unroll
        for (int i = 0; i < 4; ++i) {
            float4 e = sregv[i][jc];
            float4 o = make_float4(e.x * inv[i], e.y * inv[i], e.z * inv[i], e.w * inv[i]);
            *(float4*)(a_out + rowbase + (size_t)i * LS + j) = o;
        }
    }
}

// ---------------------------------------------------------------------------
// AV via MFMA, split-bf16 (3-pass hi/lo => fp32-grade accuracy).
// One wave per (16-i m-tile, head, K-chunk of 512). Per head GEMM:
// o[i,ch] = sum_j a[i,j] * vT[ch,j];  n-tiles {0-15,16-31,24-39(col>=8)}.
// Partial sums combined via fp32 atomicAdd into zeroed o/opt buffers.
// ---------------------------------------------------------------------------
__device__ inline void split_frag(const float* __restrict__ p, bf16x8& hi, bf16x8& lo)
{
    float4 x = *(const float4*)p;
    float4 y = *(const float4*)(p + 4);
    float f[8] = {x.x, x.y, x.z, x.w, y.x, y.y, y.z, y.w};
#pragma unroll
    for (int e = 0; e < 8; ++e) {
        __bf16 h = (__bf16)f[e];
        hi[e] = h;
        lo[e] = (__bf16)(f[e] - (float)h);
    }
}

__global__ __launch_bounds__(64) void av_mfma_kernel(
    const float* __restrict__ a, const float* __restrict__ vAllT,
    float* __restrict__ o_buf, float* __restrict__ opt_buf)
{
    const int m0 = blockIdx.x * 16;
    const int h  = blockIdx.y;
    const int ks = blockIdx.z;
    const int lane = threadIdx.x;
    const int row16 = lane & 15, kq = lane >> 4;

    const size_t kbase = (size_t)ks * 512 + kq * 8;
    const float* ap = a + ((size_t)h * LD + m0 + row16) * LS + kbase;
    const float* v0p = vAllT + ((size_t)h * 40 +  0 + row16) * LS + kbase;
    const float* v1p = vAllT + ((size_t)h * 40 + 16 + row16) * LS + kbase;
    const float* v2p = vAllT + ((size_t)h * 40 + 24 + row16) * LS + kbase;

    f32x4 acc0 = {0.f, 0.f, 0.f, 0.f};
    f32x4 acc1 = {0.f, 0.f, 0.f, 0.f};
    f32x4 acc2 = {0.f, 0.f, 0.f, 0.f};

#pragma unroll 2
    for (int kk = 0; kk < 512; kk += 32) {
        bf16x8 ah, al, bh, bl;
        split_frag(ap + kk, ah, al);

        split_frag(v0p + kk, bh, bl);
        acc0 = __builtin_amdgcn_mfma_f32_16x16x32_bf16(ah, bh, acc0, 0, 0, 0);
        acc0 = __builtin_amdgcn_mfma_f32_16x16x32_bf16(ah, bl, acc0, 0, 0, 0);
        acc0 = __builtin_amdgcn_mfma_f32_16x16x32_bf16(al, bh, acc0, 0, 0, 0);

        split_frag(v1p + kk, bh, bl);
        acc1 = __builtin_amdgcn_mfma_f32_16x16x32_bf16(ah, bh, acc1, 0, 0, 0);
        acc1 = __builtin_amdgcn_mfma_f32_16x16x32_bf16(ah, bl, acc1, 0, 0, 0);
        acc1 = __builtin_amdgcn_mfma_f32_16x16x32_bf16(al, bh, acc1, 0, 0, 0);

        split_frag(v2p + kk, bh, bl);
        acc2 = __builtin_amdgcn_mfma_f32_16x16x32_bf16(ah, bh, acc2, 0, 0, 0);
        acc2 = __builtin_amdgcn_mfma_f32_16x16x32_bf16(ah, bl, acc2, 0, 0, 0);
        acc2 = __builtin_amdgcn_mfma_f32_16x16x32_bf16(al, bh, acc2, 0, 0, 0);
    }

    // C/D layout: col = lane&15 (=channel within tile), row = kq*4 + r (i)
#pragma unroll
    for (int r = 0; r < 4; ++r) {
        int i = m0 + kq * 4 + r;
        atomicAdd(&o_buf[(size_t)i * 192 + h * 16 + row16], acc0[r]);
        atomicAdd(&opt_buf[(size_t)i * 288 + h * 24 + row16], acc1[r]);
        if (row16 >= 8)
            atomicAdd(&opt_buf[(size_t)i * 288 + h * 24 + 8 + row16], acc2[r]);
    }
}

// ---------------------------------------------------------------------------
// Finalize: cat = [o(192) | x(96) | y(96) | z(96) | norm(96)]
// ---------------------------------------------------------------------------
__global__ __launch_bounds__(192) void finalize_kernel(
    const float* __restrict__ o_buf, const float* __restrict__ opt_buf,
    const float* __restrict__ Rd, const float* __restrict__ td,
    float* __restrict__ cat)
{
    const int i = blockIdx.x, t = threadIdx.x;
    cat[i * 576 + t] = o_buf[i * 192 + t];
    if (t < 96) {
        const float* op = opt_buf + i * 288 + t * 3;
        float x = op[0] - td[i * 3 + 0];
        float y = op[1] - td[i * 3 + 1];
        float z = op[2] - td[i * 3 + 2];
        const float* R = Rd + i * 9;
        float rx = R[0] * x + R[3] * y + R[6] * z;
        float ry = R[1] * x + R[4] * y + R[7] * z;
        float rz = R[2] * x + R[5] * y + R[8] * z;
        float* cc = cat + i * 576 + 192;
        cc[t] = rx;
        cc[96 + t] = ry;
        cc[192 + t] = rz;
        cc[288 + t] = sqrtf(rx * rx + ry * ry + rz * rz + 1e-8f);
    }
}

// ---------------------------------------------------------------------------
extern "C" void kernel_launch(void* const* d_in, const int* in_sizes, int n_in,
                              void* d_out, int out_size, void* d_ws, size_t ws_size,
                              hipStream_t stream)
{
    (void)in_sizes; (void)n_in; (void)out_size; (void)ws_size;
    const float* s_dst    = (const float*)d_in[0];
    const float* s_src    = (const float*)d_in[1];
    const float* R_dst    = (const float*)d_in[2];
    const float* t_dst    = (const float*)d_in[3];
    const float* R_src    = (const float*)d_in[4];
    const float* t_src    = (const float*)d_in[5];
    const float* dst_mask = (const float*)d_in[6];
    const float* src_mask = (const float*)d_in[7];
    const float* W_q      = (const float*)d_in[8];
    const float* W_kv     = (const float*)d_in[9];
    const float* W_qp     = (const float*)d_in[10];
    const float* W_kvp    = (const float*)d_in[11];
    const float* W_out    = (const float*)d_in[12];
    const float* b_out    = (const float*)d_in[13];
    const float* head_w   = (const float*)d_in[14];

    float* ws = (float*)d_ws;
    float* q_buf   = ws;                    // 512*192   = 98304
    float* kv_buf  = q_buf   + 98304;       // 2048*384  = 786432
    float* qp_raw  = kv_buf  + 786432;      // 512*144   = 73728
    float* kvp_raw = qp_raw  + 73728;       // 2048*432  = 884736
    float* qp_rot  = kvp_raw + 884736;      // 512*144   = 73728
    float* sq_q    = qp_rot  + 73728;       // 512*12    = 6144
    float* o_buf   = sq_q    + 6144;        // 512*192   = 98304
    float* opt_buf = o_buf   + 98304;       // 512*288   = 147456  (contiguous after o_buf)
    float* cat_buf = opt_buf + 147456;      // 512*576   = 294912
    float* kT      = cat_buf + 294912;      // 12*16*2048 = 393216
    float* vAllT   = kT      + 393216;      // 12*40*2048 = 983040
    float* kpT     = vAllT   + 983040;      // 12*12*2048 = 294912
    float* sqkT    = kpT     + 294912;      // 12*2048    = 24576

    float* out_s    = (float*)d_out;              // 512*384
    float* out_a    = out_s    + 196608;          // 12*512*2048
    float* out_asd  = out_a    + 12582912;
    float* out_apts = out_asd  + 12582912;

    dim3 b256(256);
    // Projections
    sgemm_kernel<<<dim3(3, 8),  b256, 0, stream>>>(s_dst, W_q,   nullptr, q_buf,   LD, 192, CS);
    sgemm_kernel<<<dim3(3, 8),  b256, 0, stream>>>(s_dst, W_qp,  nullptr, qp_raw,  LD, 144, CS);
    sgemm_kernel<<<dim3(6, 32), b256, 0, stream>>>(s_src, W_kv,  nullptr, kv_buf,  LS, 384, CS);
    sgemm_kernel<<<dim3(7, 32), b256, 0, stream>>>(s_src, W_kvp, nullptr, kvp_raw, LS, 432, CS);
    // Rotations + squared norms (src writes transposed) + kv transpose
    rot_dst_kernel<<<LD, 64, 0, stream>>>(qp_raw, R_dst, t_dst, qp_rot, sq_q);
    rot_src_kernel<<<LS, 192, 0, stream>>>(kvp_raw, R_src, t_src, kpT, vAllT, sqkT);
    transpose_kv_kernel<<<dim3(32, 12), b256, 0, stream>>>(kv_buf, kT, vAllT);
    // Scores + softmax (+ a_sd, a_pts, a outputs)
    score_softmax_kernel<<<dim3(LD / 4, NH), b256, 0, stream>>>(
        q_buf, kT, qp_rot, kpT, sq_q, sqkT, dst_mask, src_mask, head_w,
        out_a, out_asd, out_apts);
    // Zero accumulators (o_buf + opt_buf contiguous), then MFMA AV
    hipMemsetAsync(o_buf, 0, (size_t)(98304 + 147456) * sizeof(float), stream);
    av_mfma_kernel<<<dim3(LD / 16, NH, 4), dim3(64), 0, stream>>>(out_a, vAllT, o_buf, opt_buf);
    // Inverse rotation, norms, concat
    finalize_kernel<<<LD, 192, 0, stream>>>(o_buf, opt_buf, R_dst, t_dst, cat_buf);
    // Output projection
    sgemm_kernel<<<dim3(6, 8), b256, 0, stream>>>(cat_buf, W_out, b_out, out_s, LD, CS, 576);
}

// Round 4
// 349.470 us; speedup vs baseline: 1.5980x; 1.2443x over previous
//
#include <hip/hip_runtime.h>
#include <hip/hip_bf16.h>

// Problem constants
#define LD 512
#define LS 2048
#define CS 384
#define CH 16
#define NH 12
#define PQ 4
#define PV 8
#define QCW 336   // packed [q(192) | qp(144)] row width
#define KVW 816   // packed [kv(384) | kvp(432)] row width

typedef __bf16 bf16x8 __attribute__((ext_vector_type(8)));
typedef float  f32x4  __attribute__((ext_vector_type(4)));

// ---------------------------------------------------------------------------
// Split an 8-float run into bf16 hi/lo fragments (hi + lo ~= fp32 value).
// ---------------------------------------------------------------------------
__device__ inline void split_frag(const float* __restrict__ p, bf16x8& hi, bf16x8& lo)
{
    float4 x = *(const float4*)p;
    float4 y = *(const float4*)(p + 4);
    float f[8] = {x.x, x.y, x.z, x.w, y.x, y.y, y.z, y.w};
#pragma unroll
    for (int e = 0; e < 8; ++e) {
        __bf16 h = (__bf16)f[e];
        hi[e] = h;
        lo[e] = (__bf16)(f[e] - (float)h);
    }
}

// ---------------------------------------------------------------------------
// Weight transpose: src[R][Cc] -> dst[Cc][R]. 32x32 LDS tile, 256 threads.
// ---------------------------------------------------------------------------
__global__ __launch_bounds__(256) void transpose_w_kernel(
    const float* __restrict__ src, float* __restrict__ dst, int R, int Cc)
{
    __shared__ float tile[32][33];
    const int r0 = blockIdx.x * 32, c0 = blockIdx.y * 32;
    const int tx = threadIdx.x & 31, ty = threadIdx.x >> 5;  // ty 0..7
#pragma unroll
    for (int rr = 0; rr < 32; rr += 8) {
        int r = r0 + ty + rr, c = c0 + tx;
        tile[ty + rr][tx] = (r < R && c < Cc) ? src[(size_t)r * Cc + c] : 0.f;
    }
    __syncthreads();
#pragma unroll
    for (int rr = 0; rr < 32; rr += 8) {
        int c = c0 + ty + rr, r = r0 + tx;
        if (c < Cc && r < R) dst[(size_t)c * R + r] = tile[tx][ty + rr];
    }
}

// ---------------------------------------------------------------------------
// MFMA GEMM, split-bf16 3-pass: C[M][N] = A[M][K] @ Bt[N][K]^T (+bias).
// One wave per 32x32 tile (2x2 of 16x16 MFMA sub-tiles). M%32==0, N%16==0,
// K%32==0. Layout per verified av_mfma mapping: A row = lane&15, k-quad =
// lane>>4; C col = lane&15, row = (lane>>4)*4 + r.
// ---------------------------------------------------------------------------
__global__ __launch_bounds__(64) void mfma_gemm_bt_kernel(
    const float* __restrict__ A, const float* __restrict__ Bt,
    const float* __restrict__ bias, float* __restrict__ C,
    int M, int N, int K)
{
    const int m0 = blockIdx.x * 32;
    const int n0 = blockIdx.y * 32;
    const int lane = threadIdx.x;
    const int row16 = lane & 15, kq = lane >> 4;

    const float* ap0 = A + (size_t)(m0 + row16) * K + kq * 8;
    const float* ap1 = ap0 + (size_t)16 * K;
    const float* bp0 = Bt + (size_t)(n0 + row16) * K + kq * 8;
    const float* bp1 = bp0 + (size_t)16 * K;
    const bool n1ok = (n0 + 16) < N;

    f32x4 acc00 = {0.f, 0.f, 0.f, 0.f};
    f32x4 acc10 = {0.f, 0.f, 0.f, 0.f};
    f32x4 acc01 = {0.f, 0.f, 0.f, 0.f};
    f32x4 acc11 = {0.f, 0.f, 0.f, 0.f};

    for (int k = 0; k < K; k += 32) {
        bf16x8 a0h, a0l, a1h, a1l, b0h, b0l, b1h, b1l;
        split_frag(ap0 + k, a0h, a0l);
        split_frag(ap1 + k, a1h, a1l);
        split_frag(bp0 + k, b0h, b0l);
        acc00 = __builtin_amdgcn_mfma_f32_16x16x32_bf16(a0h, b0h, acc00, 0, 0, 0);
        acc00 = __builtin_amdgcn_mfma_f32_16x16x32_bf16(a0h, b0l, acc00, 0, 0, 0);
        acc00 = __builtin_amdgcn_mfma_f32_16x16x32_bf16(a0l, b0h, acc00, 0, 0, 0);
        acc10 = __builtin_amdgcn_mfma_f32_16x16x32_bf16(a1h, b0h, acc10, 0, 0, 0);
        acc10 = __builtin_amdgcn_mfma_f32_16x16x32_bf16(a1h, b0l, acc10, 0, 0, 0);
        acc10 = __builtin_amdgcn_mfma_f32_16x16x32_bf16(a1l, b0h, acc10, 0, 0, 0);
        if (n1ok) {
            split_frag(bp1 + k, b1h, b1l);
            acc01 = __builtin_amdgcn_mfma_f32_16x16x32_bf16(a0h, b1h, acc01, 0, 0, 0);
            acc01 = __builtin_amdgcn_mfma_f32_16x16x32_bf16(a0h, b1l, acc01, 0, 0, 0);
            acc01 = __builtin_amdgcn_mfma_f32_16x16x32_bf16(a0l, b1h, acc01, 0, 0, 0);
            acc11 = __builtin_amdgcn_mfma_f32_16x16x32_bf16(a1h, b1h, acc11, 0, 0, 0);
            acc11 = __builtin_amdgcn_mfma_f32_16x16x32_bf16(a1h, b1l, acc11, 0, 0, 0);
            acc11 = __builtin_amdgcn_mfma_f32_16x16x32_bf16(a1l, b1h, acc11, 0, 0, 0);
        }
    }

    const float bv0 = bias ? bias[n0 + row16] : 0.f;
    const float bv1 = (bias && n1ok) ? bias[n0 + 16 + row16] : 0.f;
#pragma unroll
    for (int r = 0; r < 4; ++r) {
        const int mA = m0 + kq * 4 + r;
        const int mB = mA + 16;
        C[(size_t)mA * N + n0 + row16] = acc00[r] + bv0;
        C[(size_t)mB * N + n0 + row16] = acc10[r] + bv0;
        if (n1ok) {
            C[(size_t)mA * N + n0 + 16 + row16] = acc01[r] + bv1;
            C[(size_t)mB * N + n0 + 16 + row16] = acc11[r] + bv1;
        }
    }
}

// ---------------------------------------------------------------------------
// Rotate dst query points (reads packed qcat, qp part at offset 192)
// ---------------------------------------------------------------------------
__global__ __launch_bounds__(64) void rot_dst_kernel(
    const float* __restrict__ qcat, const float* __restrict__ Rd,
    const float* __restrict__ td, float* __restrict__ qp_rot,
    float* __restrict__ sqq)
{
    const int i = blockIdx.x, t = threadIdx.x;
    __shared__ float part[48];
    if (t < 48) {
        float x = qcat[i * QCW + 192 + t];
        float y = qcat[i * QCW + 192 + 48 + t];
        float z = qcat[i * QCW + 192 + 96 + t];
        const float* R = Rd + i * 9;
        float rx = R[0] * x + R[1] * y + R[2] * z + td[i * 3 + 0];
        float ry = R[3] * x + R[4] * y + R[5] * z + td[i * 3 + 1];
        float rz = R[6] * x + R[7] * y + R[8] * z + td[i * 3 + 2];
        qp_rot[i * 144 + t * 3 + 0] = rx;
        qp_rot[i * 144 + t * 3 + 1] = ry;
        qp_rot[i * 144 + t * 3 + 2] = rz;
        part[t] = rx * rx + ry * ry + rz * rz;
    }
    __syncthreads();
    if (t < NH) sqq[i * NH + t] = part[t * 4] + part[t * 4 + 1] + part[t * 4 + 2] + part[t * 4 + 3];
}

// ---------------------------------------------------------------------------
// Rotate src points (reads packed kvcat, kvp part at offset 384).
// Writes TRANSPOSED: kpT[h*12+pq*3+ax][j], vAllT[h*40+16+pv*3+ax][j], sqkT[h][j]
// ---------------------------------------------------------------------------
__global__ __launch_bounds__(192) void rot_src_kernel(
    const float* __restrict__ kvcat, const float* __restrict__ Rs,
    const float* __restrict__ ts, float* __restrict__ kpT,
    float* __restrict__ vAllT, float* __restrict__ sqkT)
{
    const int j = blockIdx.x, t = threadIdx.x;
    __shared__ float part[48];
    if (t < 144) {
        float x = kvcat[(size_t)j * KVW + 384 + t];
        float y = kvcat[(size_t)j * KVW + 384 + 144 + t];
        float z = kvcat[(size_t)j * KVW + 384 + 288 + t];
        const float* R = Rs + j * 9;
        float rx = R[0] * x + R[1] * y + R[2] * z + ts[j * 3 + 0];
        float ry = R[3] * x + R[4] * y + R[5] * z + ts[j * 3 + 1];
        float rz = R[6] * x + R[7] * y + R[8] * z + ts[j * 3 + 2];
        int h = t / 12, pp = t % 12;
        if (pp < 4) {
            size_t o = ((size_t)h * 12 + pp * 3) * LS + j;
            kpT[o] = rx; kpT[o + LS] = ry; kpT[o + 2 * LS] = rz;
            part[h * 4 + pp] = rx * rx + ry * ry + rz * rz;
        } else {
            size_t o = ((size_t)h * 40 + 16 + (pp - 4) * 3) * LS + j;
            vAllT[o] = rx; vAllT[o + LS] = ry; vAllT[o + 2 * LS] = rz;
        }
    }
    __syncthreads();
    if (t < NH) sqkT[(size_t)t * LS + j] = part[t * 4] + part[t * 4 + 1] + part[t * 4 + 2] + part[t * 4 + 3];
}

// ---------------------------------------------------------------------------
// Transpose kvcat[j][h*32+c] -> kT[h*16+c][j] (c<16) / vAllT[h*40+c-16][j]
// ---------------------------------------------------------------------------
__global__ __launch_bounds__(256) void transpose_kv_kernel(
    const float* __restrict__ kvcat, float* __restrict__ kT,
    float* __restrict__ vAllT)
{
    const int h = blockIdx.y, j0 = blockIdx.x * 64, t = threadIdx.x;
    __shared__ float tile[64][33];
#pragma unroll
    for (int r = 0; r < 2; ++r) {
        int f = t + r * 256;
        int jl = f >> 3, c4 = (f & 7) * 4;
        float4 v = *(const float4*)(kvcat + (size_t)(j0 + jl) * KVW + h * 32 + c4);
        tile[jl][c4 + 0] = v.x;
        tile[jl][c4 + 1] = v.y;
        tile[jl][c4 + 2] = v.z;
        tile[jl][c4 + 3] = v.w;
    }
    __syncthreads();
    const int jl = t & 63, cr = t >> 6;
#pragma unroll
    for (int cg = 0; cg < 8; ++cg) {
        int c = cg * 4 + cr;
        float v = tile[jl][c];
        if (c < 16) kT[((size_t)h * 16 + c) * LS + j0 + jl] = v;
        else        vAllT[((size_t)h * 40 + (c - 16)) * LS + j0 + jl] = v;
    }
}

// ---------------------------------------------------------------------------
// Scores + softmax (q read from packed qcat, stride QCW).
// ---------------------------------------------------------------------------
__global__ __launch_bounds__(256) void score_softmax_kernel(
    const float* __restrict__ qb, const float* __restrict__ kT,
    const float* __restrict__ qpb, const float* __restrict__ kpT,
    const float* __restrict__ sqq_g, const float* __restrict__ sqkT,
    const float* __restrict__ dmask, const float* __restrict__ smask,
    const float* __restrict__ head_w,
    float* __restrict__ a_out, float* __restrict__ asd_out,
    float* __restrict__ apts_out)
{
    const int h = blockIdx.y;
    const int i0 = blockIdx.x * 4;
    const int t = threadIdx.x;
    __shared__ float red[4][4];

    const float hwv = log1pf(__expf(head_w[h])) * (1.0f / 6.0f);
    const float s1 = 0.17677669529663687f;  // sqrt(1/32)
    const size_t rowbase = ((size_t)h * LD + i0) * LS;

    float4 sregv[4][2];
    float mx[4] = {-3.0e38f, -3.0e38f, -3.0e38f, -3.0e38f};

#pragma unroll
    for (int jc = 0; jc < 2; ++jc) {
        const int j = (jc * 256 + t) * 4;
        float4 sm4 = *(const float4*)(smask + j);
        float4 sqk4 = *(const float4*)(sqkT + (size_t)h * LS + j);
        float4 qk4[4], dp4[4];
#pragma unroll
        for (int i = 0; i < 4; ++i) {
            qk4[i] = make_float4(0.f, 0.f, 0.f, 0.f);
            dp4[i] = make_float4(0.f, 0.f, 0.f, 0.f);
        }
#pragma unroll
        for (int c = 0; c < 16; ++c) {
            float4 k4 = *(const float4*)(kT + ((size_t)h * 16 + c) * LS + j);
#pragma unroll
            for (int i = 0; i < 4; ++i) {
                float qv = qb[(size_t)(i0 + i) * QCW + h * CH + c];
                qk4[i].x += qv * k4.x; qk4[i].y += qv * k4.y;
                qk4[i].z += qv * k4.z; qk4[i].w += qv * k4.w;
            }
        }
#pragma unroll
        for (int d = 0; d < 12; ++d) {
            float4 p4 = *(const float4*)(kpT + ((size_t)h * 12 + d) * LS + j);
#pragma unroll
            for (int i = 0; i < 4; ++i) {
                float rv = qpb[(size_t)(i0 + i) * 144 + h * 12 + d];
                dp4[i].x += rv * p4.x; dp4[i].y += rv * p4.y;
                dp4[i].z += rv * p4.z; dp4[i].w += rv * p4.w;
            }
        }
#pragma unroll
        for (int i = 0; i < 4; ++i) {
            float sqq = sqq_g[(size_t)(i0 + i) * NH + h];
            float dm = dmask[i0 + i];
            float4 qk, pt, g, logit;
            qk.x = qk4[i].x * s1; qk.y = qk4[i].y * s1;
            qk.z = qk4[i].z * s1; qk.w = qk4[i].w * s1;
            pt.x = -0.5f * hwv * (sqq + sqk4.x - 2.f * dp4[i].x);
            pt.y = -0.5f * hwv * (sqq + sqk4.y - 2.f * dp4[i].y);
            pt.z = -0.5f * hwv * (sqq + sqk4.z - 2.f * dp4[i].z);
            pt.w = -0.5f * hwv * (sqq + sqk4.w - 2.f * dp4[i].w);
            g.x = dm * sm4.x; g.y = dm * sm4.y; g.z = dm * sm4.z; g.w = dm * sm4.w;
            size_t idx = rowbase + (size_t)i * LS + j;
            float4 asd = make_float4(qk.x * g.x, qk.y * g.y, qk.z * g.z, qk.w * g.w);
            float4 apts = make_float4(pt.x * g.x, pt.y * g.y, pt.z * g.z, pt.w * g.w);
            *(float4*)(asd_out + idx) = asd;
            *(float4*)(apts_out + idx) = apts;
            logit.x = qk.x + pt.x + 1.0e9f * (g.x - 1.0f);
            logit.y = qk.y + pt.y + 1.0e9f * (g.y - 1.0f);
            logit.z = qk.z + pt.z + 1.0e9f * (g.z - 1.0f);
            logit.w = qk.w + pt.w + 1.0e9f * (g.w - 1.0f);
            sregv[i][jc] = logit;
            mx[i] = fmaxf(mx[i], fmaxf(fmaxf(logit.x, logit.y), fmaxf(logit.z, logit.w)));
        }
    }

    const int lane = t & 63, wid = t >> 6;
#pragma unroll
    for (int i = 0; i < 4; ++i) {
        float v = mx[i];
        for (int off = 32; off > 0; off >>= 1) v = fmaxf(v, __shfl_xor(v, off));
        if (lane == 0) red[wid][i] = v;
    }
    __syncthreads();
    float M[4], sum[4] = {0.f, 0.f, 0.f, 0.f};
#pragma unroll
    for (int i = 0; i < 4; ++i)
        M[i] = fmaxf(fmaxf(red[0][i], red[1][i]), fmaxf(red[2][i], red[3][i]));
    __syncthreads();

#pragma unroll
    for (int jc = 0; jc < 2; ++jc) {
#pragma unroll
        for (int i = 0; i < 4; ++i) {
            float4 e;
            e.x = __expf(sregv[i][jc].x - M[i]);
            e.y = __expf(sregv[i][jc].y - M[i]);
            e.z = __expf(sregv[i][jc].z - M[i]);
            e.w = __expf(sregv[i][jc].w - M[i]);
            sregv[i][jc] = e;
            sum[i] += e.x + e.y + e.z + e.w;
        }
    }
#pragma unroll
    for (int i = 0; i < 4; ++i) {
        float v = sum[i];
        for (int off = 32; off > 0; off >>= 1) v += __shfl_xor(v, off);
        if (lane == 0) red[wid][i] = v;
    }
    __syncthreads();
    float inv[4];
#pragma unroll
    for (int i = 0; i < 4; ++i)
        inv[i] = 1.0f / (red[0][i] + red[1][i] + red[2][i] + red[3][i]);

#pragma unroll
    for (int jc = 0; jc < 2; ++jc) {
        const int j = (jc * 256 + t) * 4;
#pragma unroll
        for (int i = 0; i < 4; ++i) {
            float4 e = sregv[i][jc];
            float4 o = make_float4(e.x * inv[i], e.y * inv[i], e.z * inv[i], e.w * inv[i]);
            *(float4*)(a_out + rowbase + (size_t)i * LS + j) = o;
        }
    }
}

// ---------------------------------------------------------------------------
// AV via MFMA, split-bf16 (unchanged from round 3).
// ---------------------------------------------------------------------------
__global__ __launch_bounds__(64) void av_mfma_kernel(
    const float* __restrict__ a, const float* __restrict__ vAllT,
    float* __restrict__ o_buf, float* __restrict__ opt_buf)
{
    const int m0 = blockIdx.x * 16;
    const int h  = blockIdx.y;
    const int ks = blockIdx.z;
    const int lane = threadIdx.x;
    const int row16 = lane & 15, kq = lane >> 4;

    const size_t kbase = (size_t)ks * 512 + kq * 8;
    const float* ap = a + ((size_t)h * LD + m0 + row16) * LS + kbase;
    const float* v0p = vAllT + ((size_t)h * 40 +  0 + row16) * LS + kbase;
    const float* v1p = vAllT + ((size_t)h * 40 + 16 + row16) * LS + kbase;
    const float* v2p = vAllT + ((size_t)h * 40 + 24 + row16) * LS + kbase;

    f32x4 acc0 = {0.f, 0.f, 0.f, 0.f};
    f32x4 acc1 = {0.f, 0.f, 0.f, 0.f};
    f32x4 acc2 = {0.f, 0.f, 0.f, 0.f};

#pragma unroll 2
    for (int kk = 0; kk < 512; kk += 32) {
        bf16x8 ah, al, bh, bl;
        split_frag(ap + kk, ah, al);

        split_frag(v0p + kk, bh, bl);
        acc0 = __builtin_amdgcn_mfma_f32_16x16x32_bf16(ah, bh, acc0, 0, 0, 0);
        acc0 = __builtin_amdgcn_mfma_f32_16x16x32_bf16(ah, bl, acc0, 0, 0, 0);
        acc0 = __builtin_amdgcn_mfma_f32_16x16x32_bf16(al, bh, acc0, 0, 0, 0);

        split_frag(v1p + kk, bh, bl);
        acc1 = __builtin_amdgcn_mfma_f32_16x16x32_bf16(ah, bh, acc1, 0, 0, 0);
        acc1 = __builtin_amdgcn_mfma_f32_16x16x32_bf16(ah, bl, acc1, 0, 0, 0);
        acc1 = __builtin_amdgcn_mfma_f32_16x16x32_bf16(al, bh, acc1, 0, 0, 0);

        split_frag(v2p + kk, bh, bl);
        acc2 = __builtin_amdgcn_mfma_f32_16x16x32_bf16(ah, bh, acc2, 0, 0, 0);
        acc2 = __builtin_amdgcn_mfma_f32_16x16x32_bf16(ah, bl, acc2, 0, 0, 0);
        acc2 = __builtin_amdgcn_mfma_f32_16x16x32_bf16(al, bh, acc2, 0, 0, 0);
    }

#pragma unroll
    for (int r = 0; r < 4; ++r) {
        int i = m0 + kq * 4 + r;
        atomicAdd(&o_buf[(size_t)i * 192 + h * 16 + row16], acc0[r]);
        atomicAdd(&opt_buf[(size_t)i * 288 + h * 24 + row16], acc1[r]);
        if (row16 >= 8)
            atomicAdd(&opt_buf[(size_t)i * 288 + h * 24 + 8 + row16], acc2[r]);
    }
}

// ---------------------------------------------------------------------------
// Finalize: cat = [o(192) | x(96) | y(96) | z(96) | norm(96)]
// ---------------------------------------------------------------------------
__global__ __launch_bounds__(192) void finalize_kernel(
    const float* __restrict__ o_buf, const float* __restrict__ opt_buf,
    const float* __restrict__ Rd, const float* __restrict__ td,
    float* __restrict__ cat)
{
    const int i = blockIdx.x, t = threadIdx.x;
    cat[i * 576 + t] = o_buf[i * 192 + t];
    if (t < 96) {
        const float* op = opt_buf + i * 288 + t * 3;
        float x = op[0] - td[i * 3 + 0];
        float y = op[1] - td[i * 3 + 1];
        float z = op[2] - td[i * 3 + 2];
        const float* R = Rd + i * 9;
        float rx = R[0] * x + R[3] * y + R[6] * z;
        float ry = R[1] * x + R[4] * y + R[7] * z;
        float rz = R[2] * x + R[5] * y + R[8] * z;
        float* cc = cat + i * 576 + 192;
        cc[t] = rx;
        cc[96 + t] = ry;
        cc[192 + t] = rz;
        cc[288 + t] = sqrtf(rx * rx + ry * ry + rz * rz + 1e-8f);
    }
}

// ---------------------------------------------------------------------------
extern "C" void kernel_launch(void* const* d_in, const int* in_sizes, int n_in,
                              void* d_out, int out_size, void* d_ws, size_t ws_size,
                              hipStream_t stream)
{
    (void)in_sizes; (void)n_in; (void)out_size; (void)ws_size;
    const float* s_dst    = (const float*)d_in[0];
    const float* s_src    = (const float*)d_in[1];
    const float* R_dst    = (const float*)d_in[2];
    const float* t_dst    = (const float*)d_in[3];
    const float* R_src    = (const float*)d_in[4];
    const float* t_src    = (const float*)d_in[5];
    const float* dst_mask = (const float*)d_in[6];
    const float* src_mask = (const float*)d_in[7];
    const float* W_q      = (const float*)d_in[8];
    const float* W_kv     = (const float*)d_in[9];
    const float* W_qp     = (const float*)d_in[10];
    const float* W_kvp    = (const float*)d_in[11];
    const float* W_out    = (const float*)d_in[12];
    const float* b_out    = (const float*)d_in[13];
    const float* head_w   = (const float*)d_in[14];

    float* ws = (float*)d_ws;
    float* qcat    = ws;                    // 512*336    = 172032
    float* kvcat   = qcat    + 172032;      // 2048*816   = 1671168
    float* qp_rot  = kvcat   + 1671168;     // 512*144    = 73728
    float* sq_q    = qp_rot  + 73728;       // 512*12     = 6144
    float* o_buf   = sq_q    + 6144;        // 512*192    = 98304
    float* opt_buf = o_buf   + 98304;       // 512*288    = 147456 (contiguous after o_buf)
    float* cat_buf = opt_buf + 147456;      // 512*576    = 294912
    float* kT      = cat_buf + 294912;      // 12*16*2048 = 393216
    float* vAllT   = kT      + 393216;      // 12*40*2048 = 983040
    float* kpT     = vAllT   + 983040;      // 12*12*2048 = 294912
    float* sqkT    = kpT     + 294912;      // 12*2048    = 24576
    float* Wt_qc   = sqkT    + 24576;       // 336*384    = 129024
    float* Wt_kvc  = Wt_qc   + 129024;      // 816*384    = 313344
    float* Wt_out  = Wt_kvc  + 313344;      // 384*576    = 221184

    float* out_s    = (float*)d_out;              // 512*384
    float* out_a    = out_s    + 196608;          // 12*512*2048
    float* out_asd  = out_a    + 12582912;
    float* out_apts = out_asd  + 12582912;

    dim3 b256(256);
    // Weight transposes into packed Bt layouts
    transpose_w_kernel<<<dim3(12,  6), b256, 0, stream>>>(W_q,   Wt_qc,              384, 192);
    transpose_w_kernel<<<dim3(12,  5), b256, 0, stream>>>(W_qp,  Wt_qc  + 192 * 384, 384, 144);
    transpose_w_kernel<<<dim3(12, 12), b256, 0, stream>>>(W_kv,  Wt_kvc,             384, 384);
    transpose_w_kernel<<<dim3(12, 14), b256, 0, stream>>>(W_kvp, Wt_kvc + 384 * 384, 384, 432);
    transpose_w_kernel<<<dim3(18, 12), b256, 0, stream>>>(W_out, Wt_out,             576, 384);
    // Projections via MFMA split-bf16
    mfma_gemm_bt_kernel<<<dim3(16, 11), dim3(64), 0, stream>>>(s_dst, Wt_qc,  nullptr, qcat,  LD, QCW, CS);
    mfma_gemm_bt_kernel<<<dim3(64, 26), dim3(64), 0, stream>>>(s_src, Wt_kvc, nullptr, kvcat, LS, KVW, CS);
    // Rotations + squared norms (src writes transposed) + kv transpose
    rot_dst_kernel<<<LD, 64, 0, stream>>>(qcat, R_dst, t_dst, qp_rot, sq_q);
    rot_src_kernel<<<LS, 192, 0, stream>>>(kvcat, R_src, t_src, kpT, vAllT, sqkT);
    transpose_kv_kernel<<<dim3(32, 12), b256, 0, stream>>>(kvcat, kT, vAllT);
    // Scores + softmax (+ a_sd, a_pts, a outputs)
    score_softmax_kernel<<<dim3(LD / 4, NH), b256, 0, stream>>>(
        qcat, kT, qp_rot, kpT, sq_q, sqkT, dst_mask, src_mask, head_w,
        out_a, out_asd, out_apts);
    // Zero accumulators (o_buf + opt_buf contiguous), then MFMA AV
    hipMemsetAsync(o_buf, 0, (size_t)(98304 + 147456) * sizeof(float), stream);
    av_mfma_kernel<<<dim3(LD / 16, NH, 4), dim3(64), 0, stream>>>(out_a, vAllT, o_buf, opt_buf);
    // Inverse rotation, norms, concat
    finalize_kernel<<<LD, 192, 0, stream>>>(o_buf, opt_buf, R_dst, t_dst, cat_buf);
    // Output projection via MFMA split-bf16 (+bias)
    mfma_gemm_bt_kernel<<<dim3(16, 12), dim3(64), 0, stream>>>(cat_buf, Wt_out, b_out, out_s, LD, CS, 576);
}

// Round 7
// 327.698 us; speedup vs baseline: 1.7042x; 1.0664x over previous
//
#include <hip/hip_runtime.h>
#include <hip/hip_bf16.h>

// Problem constants
#define LD 512
#define LS 2048
#define CS 384
#define CH 16
#define NH 12
#define PQ 4
#define PV 8
#define QCW 336   // packed [q(192) | qp(144)] row width
#define KVW 816   // packed [kv(384) | kvp(432)] row width

typedef __bf16 bf16x8 __attribute__((ext_vector_type(8)));
typedef float  f32x4  __attribute__((ext_vector_type(4)));

// ---------------------------------------------------------------------------
// Split an 8-float run into bf16 hi/lo fragments (hi + lo ~= fp32 value).
// ---------------------------------------------------------------------------
__device__ inline void split_frag(const float* __restrict__ p, bf16x8& hi, bf16x8& lo)
{
    float4 x = *(const float4*)p;
    float4 y = *(const float4*)(p + 4);
    float f[8] = {x.x, x.y, x.z, x.w, y.x, y.y, y.z, y.w};
#pragma unroll
    for (int e = 0; e < 8; ++e) {
        __bf16 h = (__bf16)f[e];
        hi[e] = h;
        lo[e] = (__bf16)(f[e] - (float)h);
    }
}

// ---------------------------------------------------------------------------
// Weight transpose: src[R][Cc] -> dst[Cc][R]. 32x32 LDS tile, 256 threads.
// ---------------------------------------------------------------------------
__global__ __launch_bounds__(256) void transpose_w_kernel(
    const float* __restrict__ src, float* __restrict__ dst, int R, int Cc)
{
    __shared__ float tile[32][33];
    const int r0 = blockIdx.x * 32, c0 = blockIdx.y * 32;
    const int tx = threadIdx.x & 31, ty = threadIdx.x >> 5;  // ty 0..7
#pragma unroll
    for (int rr = 0; rr < 32; rr += 8) {
        int r = r0 + ty + rr, c = c0 + tx;
        tile[ty + rr][tx] = (r < R && c < Cc) ? src[(size_t)r * Cc + c] : 0.f;
    }
    __syncthreads();
#pragma unroll
    for (int rr = 0; rr < 32; rr += 8) {
        int c = c0 + ty + rr, r = r0 + tx;
        if (c < Cc && r < R) dst[(size_t)c * R + r] = tile[tx][ty + rr];
    }
}

// ---------------------------------------------------------------------------
// MFMA GEMM, split-bf16 3-pass: C[M][N] = A[M][K] @ Bt[N][K]^T (+bias).
// ---------------------------------------------------------------------------
__global__ __launch_bounds__(64) void mfma_gemm_bt_kernel(
    const float* __restrict__ A, const float* __restrict__ Bt,
    const float* __restrict__ bias, float* __restrict__ C,
    int M, int N, int K)
{
    const int m0 = blockIdx.x * 32;
    const int n0 = blockIdx.y * 32;
    const int lane = threadIdx.x;
    const int row16 = lane & 15, kq = lane >> 4;

    const float* ap0 = A + (size_t)(m0 + row16) * K + kq * 8;
    const float* ap1 = ap0 + (size_t)16 * K;
    const float* bp0 = Bt + (size_t)(n0 + row16) * K + kq * 8;
    const float* bp1 = bp0 + (size_t)16 * K;
    const bool n1ok = (n0 + 16) < N;

    f32x4 acc00 = {0.f, 0.f, 0.f, 0.f};
    f32x4 acc10 = {0.f, 0.f, 0.f, 0.f};
    f32x4 acc01 = {0.f, 0.f, 0.f, 0.f};
    f32x4 acc11 = {0.f, 0.f, 0.f, 0.f};

    for (int k = 0; k < K; k += 32) {
        bf16x8 a0h, a0l, a1h, a1l, b0h, b0l, b1h, b1l;
        split_frag(ap0 + k, a0h, a0l);
        split_frag(ap1 + k, a1h, a1l);
        split_frag(bp0 + k, b0h, b0l);
        acc00 = __builtin_amdgcn_mfma_f32_16x16x32_bf16(a0h, b0h, acc00, 0, 0, 0);
        acc00 = __builtin_amdgcn_mfma_f32_16x16x32_bf16(a0h, b0l, acc00, 0, 0, 0);
        acc00 = __builtin_amdgcn_mfma_f32_16x16x32_bf16(a0l, b0h, acc00, 0, 0, 0);
        acc10 = __builtin_amdgcn_mfma_f32_16x16x32_bf16(a1h, b0h, acc10, 0, 0, 0);
        acc10 = __builtin_amdgcn_mfma_f32_16x16x32_bf16(a1h, b0l, acc10, 0, 0, 0);
        acc10 = __builtin_amdgcn_mfma_f32_16x16x32_bf16(a1l, b0h, acc10, 0, 0, 0);
        if (n1ok) {
            split_frag(bp1 + k, b1h, b1l);
            acc01 = __builtin_amdgcn_mfma_f32_16x16x32_bf16(a0h, b1h, acc01, 0, 0, 0);
            acc01 = __builtin_amdgcn_mfma_f32_16x16x32_bf16(a0h, b1l, acc01, 0, 0, 0);
            acc01 = __builtin_amdgcn_mfma_f32_16x16x32_bf16(a0l, b1h, acc01, 0, 0, 0);
            acc11 = __builtin_amdgcn_mfma_f32_16x16x32_bf16(a1h, b1h, acc11, 0, 0, 0);
            acc11 = __builtin_amdgcn_mfma_f32_16x16x32_bf16(a1h, b1l, acc11, 0, 0, 0);
            acc11 = __builtin_amdgcn_mfma_f32_16x16x32_bf16(a1l, b1h, acc11, 0, 0, 0);
        }
    }

    const float bv0 = bias ? bias[n0 + row16] : 0.f;
    const float bv1 = (bias && n1ok) ? bias[n0 + 16 + row16] : 0.f;
#pragma unroll
    for (int r = 0; r < 4; ++r) {
        const int mA = m0 + kq * 4 + r;
        const int mB = mA + 16;
        C[(size_t)mA * N + n0 + row16] = acc00[r] + bv0;
        C[(size_t)mB * N + n0 + row16] = acc10[r] + bv0;
        if (n1ok) {
            C[(size_t)mA * N + n0 + 16 + row16] = acc01[r] + bv1;
            C[(size_t)mB * N + n0 + 16 + row16] = acc11[r] + bv1;
        }
    }
}

// ---------------------------------------------------------------------------
// Rotate dst query points (reads packed qcat, qp part at offset 192)
// qp_rot layout: [i][p*3+ax] with p = h*4+pq  (matches kpT row indexing)
// ---------------------------------------------------------------------------
__global__ __launch_bounds__(64) void rot_dst_kernel(
    const float* __restrict__ qcat, const float* __restrict__ Rd,
    const float* __restrict__ td, float* __restrict__ qp_rot,
    float* __restrict__ sqq)
{
    const int i = blockIdx.x, t = threadIdx.x;
    __shared__ float part[48];
    if (t < 48) {
        float x = qcat[i * QCW + 192 + t];
        float y = qcat[i * QCW + 192 + 48 + t];
        float z = qcat[i * QCW + 192 + 96 + t];
        const float* R = Rd + i * 9;
        float rx = R[0] * x + R[1] * y + R[2] * z + td[i * 3 + 0];
        float ry = R[3] * x + R[4] * y + R[5] * z + td[i * 3 + 1];
        float rz = R[6] * x + R[7] * y + R[8] * z + td[i * 3 + 2];
        qp_rot[i * 144 + t * 3 + 0] = rx;
        qp_rot[i * 144 + t * 3 + 1] = ry;
        qp_rot[i * 144 + t * 3 + 2] = rz;
        part[t] = rx * rx + ry * ry + rz * rz;
    }
    __syncthreads();
    if (t < NH) sqq[i * NH + t] = part[t * 4] + part[t * 4 + 1] + part[t * 4 + 2] + part[t * 4 + 3];
}

// ---------------------------------------------------------------------------
// Rotate src points (reads packed kvcat, kvp part at offset 384).
// Writes TRANSPOSED: kpT[h*12+pq*3+ax][j], vAllT[h*40+16+pv*3+ax][j], sqkT[h][j]
// ---------------------------------------------------------------------------
__global__ __launch_bounds__(192) void rot_src_kernel(
    const float* __restrict__ kvcat, const float* __restrict__ Rs,
    const float* __restrict__ ts, float* __restrict__ kpT,
    float* __restrict__ vAllT, float* __restrict__ sqkT)
{
    const int j = blockIdx.x, t = threadIdx.x;
    __shared__ float part[48];
    if (t < 144) {
        float x = kvcat[(size_t)j * KVW + 384 + t];
        float y = kvcat[(size_t)j * KVW + 384 + 144 + t];
        float z = kvcat[(size_t)j * KVW + 384 + 288 + t];
        const float* R = Rs + j * 9;
        float rx = R[0] * x + R[1] * y + R[2] * z + ts[j * 3 + 0];
        float ry = R[3] * x + R[4] * y + R[5] * z + ts[j * 3 + 1];
        float rz = R[6] * x + R[7] * y + R[8] * z + ts[j * 3 + 2];
        int h = t / 12, pp = t % 12;
        if (pp < 4) {
            size_t o = ((size_t)h * 12 + pp * 3) * LS + j;
            kpT[o] = rx; kpT[o + LS] = ry; kpT[o + 2 * LS] = rz;
            part[h * 4 + pp] = rx * rx + ry * ry + rz * rz;
        } else {
            size_t o = ((size_t)h * 40 + 16 + (pp - 4) * 3) * LS + j;
            vAllT[o] = rx; vAllT[o + LS] = ry; vAllT[o + 2 * LS] = rz;
        }
    }
    __syncthreads();
    if (t < NH) sqkT[(size_t)t * LS + j] = part[t * 4] + part[t * 4 + 1] + part[t * 4 + 2] + part[t * 4 + 3];
}

// ---------------------------------------------------------------------------
// Transpose kvcat[j][h*32+c] -> kT[h*16+c][j] (c<16) / vAllT[h*40+c-16][j]
// ---------------------------------------------------------------------------
__global__ __launch_bounds__(256) void transpose_kv_kernel(
    const float* __restrict__ kvcat, float* __restrict__ kT,
    float* __restrict__ vAllT)
{
    const int h = blockIdx.y, j0 = blockIdx.x * 64, t = threadIdx.x;
    __shared__ float tile[64][33];
#pragma unroll
    for (int r = 0; r < 2; ++r) {
        int f = t + r * 256;
        int jl = f >> 3, c4 = (f & 7) * 4;
        float4 v = *(const float4*)(kvcat + (size_t)(j0 + jl) * KVW + h * 32 + c4);
        tile[jl][c4 + 0] = v.x;
        tile[jl][c4 + 1] = v.y;
        tile[jl][c4 + 2] = v.z;
        tile[jl][c4 + 3] = v.w;
    }
    __syncthreads();
    const int jl = t & 63, cr = t >> 6;
#pragma unroll
    for (int cg = 0; cg < 8; ++cg) {
        int c = cg * 4 + cr;
        float v = tile[jl][c];
        if (c < 16) kT[((size_t)h * 16 + c) * LS + j0 + jl] = v;
        else        vAllT[((size_t)h * 40 + (c - 16)) * LS + j0 + jl] = v;
    }
}

// ---------------------------------------------------------------------------
// Scores + softmax. LDS-staged q-side (q from qcat, qp from ROTATED qp_rot)
// + coalesced transposed k-side. asd/apts are pure-write -> nontemporal
// stores; a_out stays cached (av_mfma re-reads it from L2).
// ---------------------------------------------------------------------------
__global__ __launch_bounds__(256) void score_softmax_kernel(
    const float* __restrict__ qb, const float* __restrict__ kT,
    const float* __restrict__ qpb, const float* __restrict__ kpT,
    const float* __restrict__ sqq_g, const float* __restrict__ sqkT,
    const float* __restrict__ dmask, const float* __restrict__ smask,
    const float* __restrict__ head_w,
    float* __restrict__ a_out, float* __restrict__ asd_out,
    float* __restrict__ apts_out)
{
    const int h = blockIdx.y;
    const int i0 = blockIdx.x * 4;
    const int t = threadIdx.x;

    __shared__ float qs[4][32];   // [i][0:16]=q, [16:28]=rotated qp, pad
    __shared__ float sqq_s[4];
    __shared__ float dm_s[4];
    __shared__ float red[4][4];

    if (t < 128) {
        int i = t >> 5, c = t & 31;
        float v = 0.f;
        if (c < 16)      v = qb[(size_t)(i0 + i) * QCW + h * CH + c];
        else if (c < 28) v = qpb[(size_t)(i0 + i) * 144 + h * 12 + (c - 16)];
        qs[i][c] = v;
    } else if (t < 132) {
        int i = t - 128;
        sqq_s[i] = sqq_g[(size_t)(i0 + i) * NH + h];
        dm_s[i] = dmask[i0 + i];
    }
    const float hwv = log1pf(__expf(head_w[h])) * (1.0f / 6.0f);
    const float s1 = 0.17677669529663687f;  // sqrt(1/32)
    const size_t rowbase = ((size_t)h * LD + i0) * LS;
    __syncthreads();

    float4 sregv[4][2];
    float mx[4] = {-3.0e38f, -3.0e38f, -3.0e38f, -3.0e38f};

#pragma unroll
    for (int jc = 0; jc < 2; ++jc) {
        const int j = (jc * 256 + t) * 4;
        float4 sm4 = *(const float4*)(smask + j);
        float4 sqk4 = *(const float4*)(sqkT + (size_t)h * LS + j);

        // Burst-load all 16 k rows (independent 16B loads -> deep MLP)
        float4 kk[16];
#pragma unroll
        for (int c = 0; c < 16; ++c)
            kk[c] = *(const float4*)(kT + ((size_t)h * 16 + c) * LS + j);

        float4 qk4[4];
#pragma unroll
        for (int i = 0; i < 4; ++i) {
            const float4* q4 = (const float4*)&qs[i][0];
            float4 q0 = q4[0], q1 = q4[1], q2 = q4[2], q3 = q4[3];
            float4 a;
            a.x = q0.x * kk[0].x + q0.y * kk[1].x + q0.z * kk[2].x + q0.w * kk[3].x
                + q1.x * kk[4].x + q1.y * kk[5].x + q1.z * kk[6].x + q1.w * kk[7].x
                + q2.x * kk[8].x + q2.y * kk[9].x + q2.z * kk[10].x + q2.w * kk[11].x
                + q3.x * kk[12].x + q3.y * kk[13].x + q3.z * kk[14].x + q3.w * kk[15].x;
            a.y = q0.x * kk[0].y + q0.y * kk[1].y + q0.z * kk[2].y + q0.w * kk[3].y
                + q1.x * kk[4].y + q1.y * kk[5].y + q1.z * kk[6].y + q1.w * kk[7].y
                + q2.x * kk[8].y + q2.y * kk[9].y + q2.z * kk[10].y + q2.w * kk[11].y
                + q3.x * kk[12].y + q3.y * kk[13].y + q3.z * kk[14].y + q3.w * kk[15].y;
            a.z = q0.x * kk[0].z + q0.y * kk[1].z + q0.z * kk[2].z + q0.w * kk[3].z
                + q1.x * kk[4].z + q1.y * kk[5].z + q1.z * kk[6].z + q1.w * kk[7].z
                + q2.x * kk[8].z + q2.y * kk[9].z + q2.z * kk[10].z + q2.w * kk[11].z
                + q3.x * kk[12].z + q3.y * kk[13].z + q3.z * kk[14].z + q3.w * kk[15].z;
            a.w = q0.x * kk[0].w + q0.y * kk[1].w + q0.z * kk[2].w + q0.w * kk[3].w
                + q1.x * kk[4].w + q1.y * kk[5].w + q1.z * kk[6].w + q1.w * kk[7].w
                + q2.x * kk[8].w + q2.y * kk[9].w + q2.z * kk[10].w + q2.w * kk[11].w
                + q3.x * kk[12].w + q3.y * kk[13].w + q3.z * kk[14].w + q3.w * kk[15].w;
            qk4[i] = a;
        }

        // Burst-load all 12 kp rows
        float4 pp[12];
#pragma unroll
        for (int d = 0; d < 12; ++d)
            pp[d] = *(const float4*)(kpT + ((size_t)h * 12 + d) * LS + j);

        float4 dp4[4];
#pragma unroll
        for (int i = 0; i < 4; ++i) {
            const float4* r4 = (const float4*)&qs[i][16];
            float4 r0 = r4[0], r1 = r4[1], r2 = r4[2];
            float4 d;
            d.x = r0.x * pp[0].x + r0.y * pp[1].x + r0.z * pp[2].x + r0.w * pp[3].x
                + r1.x * pp[4].x + r1.y * pp[5].x + r1.z * pp[6].x + r1.w * pp[7].x
                + r2.x * pp[8].x + r2.y * pp[9].x + r2.z * pp[10].x + r2.w * pp[11].x;
            d.y = r0.x * pp[0].y + r0.y * pp[1].y + r0.z * pp[2].y + r0.w * pp[3].y
                + r1.x * pp[4].y + r1.y * pp[5].y + r1.z * pp[6].y + r1.w * pp[7].y
                + r2.x * pp[8].y + r2.y * pp[9].y + r2.z * pp[10].y + r2.w * pp[11].y;
            d.z = r0.x * pp[0].z + r0.y * pp[1].z + r0.z * pp[2].z + r0.w * pp[3].z
                + r1.x * pp[4].z + r1.y * pp[5].z + r1.z * pp[6].z + r1.w * pp[7].z
                + r2.x * pp[8].z + r2.y * pp[9].z + r2.z * pp[10].z + r2.w * pp[11].z;
            d.w = r0.x * pp[0].w + r0.y * pp[1].w + r0.z * pp[2].w + r0.w * pp[3].w
                + r1.x * pp[4].w + r1.y * pp[5].w + r1.z * pp[6].w + r1.w * pp[7].w
                + r2.x * pp[8].w + r2.y * pp[9].w + r2.z * pp[10].w + r2.w * pp[11].w;
            dp4[i] = d;
        }

#pragma unroll
        for (int i = 0; i < 4; ++i) {
            float sqq = sqq_s[i];
            float dm = dm_s[i];
            float4 qk, pt, g, logit;
            qk.x = qk4[i].x * s1; qk.y = qk4[i].y * s1;
            qk.z = qk4[i].z * s1; qk.w = qk4[i].w * s1;
            pt.x = -0.5f * hwv * (sqq + sqk4.x - 2.f * dp4[i].x);
            pt.y = -0.5f * hwv * (sqq + sqk4.y - 2.f * dp4[i].y);
            pt.z = -0.5f * hwv * (sqq + sqk4.z - 2.f * dp4[i].z);
            pt.w = -0.5f * hwv * (sqq + sqk4.w - 2.f * dp4[i].w);
            g.x = dm * sm4.x; g.y = dm * sm4.y; g.z = dm * sm4.z; g.w = dm * sm4.w;
            size_t idx = rowbase + (size_t)i * LS + j;
            f32x4 asd = {qk.x * g.x, qk.y * g.y, qk.z * g.z, qk.w * g.w};
            f32x4 apts = {pt.x * g.x, pt.y * g.y, pt.z * g.z, pt.w * g.w};
            __builtin_nontemporal_store(asd, (f32x4*)(asd_out + idx));
            __builtin_nontemporal_store(apts, (f32x4*)(apts_out + idx));
            logit.x = qk.x + pt.x + 1.0e9f * (g.x - 1.0f);
            logit.y = qk.y + pt.y + 1.0e9f * (g.y - 1.0f);
            logit.z = qk.z + pt.z + 1.0e9f * (g.z - 1.0f);
            logit.w = qk.w + pt.w + 1.0e9f * (g.w - 1.0f);
            sregv[i][jc] = logit;
            mx[i] = fmaxf(mx[i], fmaxf(fmaxf(logit.x, logit.y), fmaxf(logit.z, logit.w)));
        }
    }

    const int lane = t & 63, wid = t >> 6;
#pragma unroll
    for (int i = 0; i < 4; ++i) {
        float v = mx[i];
        for (int off = 32; off > 0; off >>= 1) v = fmaxf(v, __shfl_xor(v, off));
        if (lane == 0) red[wid][i] = v;
    }
    __syncthreads();
    float M[4], sum[4] = {0.f, 0.f, 0.f, 0.f};
#pragma unroll
    for (int i = 0; i < 4; ++i)
        M[i] = fmaxf(fmaxf(red[0][i], red[1][i]), fmaxf(red[2][i], red[3][i]));
    __syncthreads();

#pragma unroll
    for (int jc = 0; jc < 2; ++jc) {
#pragma unroll
        for (int i = 0; i < 4; ++i) {
            float4 e;
            e.x = __expf(sregv[i][jc].x - M[i]);
            e.y = __expf(sregv[i][jc].y - M[i]);
            e.z = __expf(sregv[i][jc].z - M[i]);
            e.w = __expf(sregv[i][jc].w - M[i]);
            sregv[i][jc] = e;
            sum[i] += e.x + e.y + e.z + e.w;
        }
    }
#pragma unroll
    for (int i = 0; i < 4; ++i) {
        float v = sum[i];
        for (int off = 32; off > 0; off >>= 1) v += __shfl_xor(v, off);
        if (lane == 0) red[wid][i] = v;
    }
    __syncthreads();
    float inv[4];
#pragma unroll
    for (int i = 0; i < 4; ++i)
        inv[i] = 1.0f / (red[0][i] + red[1][i] + red[2][i] + red[3][i]);

#pragma unroll
    for (int jc = 0; jc < 2; ++jc) {
        const int j = (jc * 256 + t) * 4;
#pragma unroll
        for (int i = 0; i < 4; ++i) {
            float4 e = sregv[i][jc];
            float4 o = make_float4(e.x * inv[i], e.y * inv[i], e.z * inv[i], e.w * inv[i]);
            *(float4*)(a_out + rowbase + (size_t)i * LS + j) = o;
        }
    }
}

// ---------------------------------------------------------------------------
// AV via MFMA, split-bf16 (unchanged).
// ---------------------------------------------------------------------------
__global__ __launch_bounds__(64) void av_mfma_kernel(
    const float* __restrict__ a, const float* __restrict__ vAllT,
    float* __restrict__ o_buf, float* __restrict__ opt_buf)
{
    const int m0 = blockIdx.x * 16;
    const int h  = blockIdx.y;
    const int ks = blockIdx.z;
    const int lane = threadIdx.x;
    const int row16 = lane & 15, kq = lane >> 4;

    const size_t kbase = (size_t)ks * 512 + kq * 8;
    const float* ap = a + ((size_t)h * LD + m0 + row16) * LS + kbase;
    const float* v0p = vAllT + ((size_t)h * 40 +  0 + row16) * LS + kbase;
    const float* v1p = vAllT + ((size_t)h * 40 + 16 + row16) * LS + kbase;
    const float* v2p = vAllT + ((size_t)h * 40 + 24 + row16) * LS + kbase;

    f32x4 acc0 = {0.f, 0.f, 0.f, 0.f};
    f32x4 acc1 = {0.f, 0.f, 0.f, 0.f};
    f32x4 acc2 = {0.f, 0.f, 0.f, 0.f};

#pragma unroll 2
    for (int kk = 0; kk < 512; kk += 32) {
        bf16x8 ah, al, bh, bl;
        split_frag(ap + kk, ah, al);

        split_frag(v0p + kk, bh, bl);
        acc0 = __builtin_amdgcn_mfma_f32_16x16x32_bf16(ah, bh, acc0, 0, 0, 0);
        acc0 = __builtin_amdgcn_mfma_f32_16x16x32_bf16(ah, bl, acc0, 0, 0, 0);
        acc0 = __builtin_amdgcn_mfma_f32_16x16x32_bf16(al, bh, acc0, 0, 0, 0);

        split_frag(v1p + kk, bh, bl);
        acc1 = __builtin_amdgcn_mfma_f32_16x16x32_bf16(ah, bh, acc1, 0, 0, 0);
        acc1 = __builtin_amdgcn_mfma_f32_16x16x32_bf16(ah, bl, acc1, 0, 0, 0);
        acc1 = __builtin_amdgcn_mfma_f32_16x16x32_bf16(al, bh, acc1, 0, 0, 0);

        split_frag(v2p + kk, bh, bl);
        acc2 = __builtin_amdgcn_mfma_f32_16x16x32_bf16(ah, bh, acc2, 0, 0, 0);
        acc2 = __builtin_amdgcn_mfma_f32_16x16x32_bf16(ah, bl, acc2, 0, 0, 0);
        acc2 = __builtin_amdgcn_mfma_f32_16x16x32_bf16(al, bh, acc2, 0, 0, 0);
    }

#pragma unroll
    for (int r = 0; r < 4; ++r) {
        int i = m0 + kq * 4 + r;
        atomicAdd(&o_buf[(size_t)i * 192 + h * 16 + row16], acc0[r]);
        atomicAdd(&opt_buf[(size_t)i * 288 + h * 24 + row16], acc1[r]);
        if (row16 >= 8)
            atomicAdd(&opt_buf[(size_t)i * 288 + h * 24 + 8 + row16], acc2[r]);
    }
}

// ---------------------------------------------------------------------------
// Finalize: cat = [o(192) | x(96) | y(96) | z(96) | norm(96)]
// ---------------------------------------------------------------------------
__global__ __launch_bounds__(192) void finalize_kernel(
    const float* __restrict__ o_buf, const float* __restrict__ opt_buf,
    const float* __restrict__ Rd, const float* __restrict__ td,
    float* __restrict__ cat)
{
    const int i = blockIdx.x, t = threadIdx.x;
    cat[i * 576 + t] = o_buf[i * 192 + t];
    if (t < 96) {
        const float* op = opt_buf + i * 288 + t * 3;
        float x = op[0] - td[i * 3 + 0];
        float y = op[1] - td[i * 3 + 1];
        float z = op[2] - td[i * 3 + 2];
        const float* R = Rd + i * 9;
        float rx = R[0] * x + R[3] * y + R[6] * z;
        float ry = R[1] * x + R[4] * y + R[7] * z;
        float rz = R[2] * x + R[5] * y + R[8] * z;
        float* cc = cat + i * 576 + 192;
        cc[t] = rx;
        cc[96 + t] = ry;
        cc[192 + t] = rz;
        cc[288 + t] = sqrtf(rx * rx + ry * ry + rz * rz + 1e-8f);
    }
}

// ---------------------------------------------------------------------------
extern "C" void kernel_launch(void* const* d_in, const int* in_sizes, int n_in,
                              void* d_out, int out_size, void* d_ws, size_t ws_size,
                              hipStream_t stream)
{
    (void)in_sizes; (void)n_in; (void)out_size; (void)ws_size;
    const float* s_dst    = (const float*)d_in[0];
    const float* s_src    = (const float*)d_in[1];
    const float* R_dst    = (const float*)d_in[2];
    const float* t_dst    = (const float*)d_in[3];
    const float* R_src    = (const float*)d_in[4];
    const float* t_src    = (const float*)d_in[5];
    const float* dst_mask = (const float*)d_in[6];
    const float* src_mask = (const float*)d_in[7];
    const float* W_q      = (const float*)d_in[8];
    const float* W_kv     = (const float*)d_in[9];
    const float* W_qp     = (const float*)d_in[10];
    const float* W_kvp    = (const float*)d_in[11];
    const float* W_out    = (const float*)d_in[12];
    const float* b_out    = (const float*)d_in[13];
    const float* head_w   = (const float*)d_in[14];

    float* ws = (float*)d_ws;
    float* qcat    = ws;                    // 512*336    = 172032
    float* kvcat   = qcat    + 172032;      // 2048*816   = 1671168
    float* qp_rot  = kvcat   + 1671168;     // 512*144    = 73728
    float* sq_q    = qp_rot  + 73728;       // 512*12     = 6144
    float* o_buf   = sq_q    + 6144;        // 512*192    = 98304
    float* opt_buf = o_buf   + 98304;       // 512*288    = 147456 (contiguous after o_buf)
    float* cat_buf = opt_buf + 147456;      // 512*576    = 294912
    float* kT      = cat_buf + 294912;      // 12*16*2048 = 393216
    float* vAllT   = kT      + 393216;      // 12*40*2048 = 983040
    float* kpT     = vAllT   + 983040;      // 12*12*2048 = 294912
    float* sqkT    = kpT     + 294912;      // 12*2048    = 24576
    float* Wt_qc   = sqkT    + 24576;       // 336*384    = 129024
    float* Wt_kvc  = Wt_qc   + 129024;      // 816*384    = 313344
    float* Wt_out  = Wt_kvc  + 313344;      // 384*576    = 221184

    float* out_s    = (float*)d_out;              // 512*384
    float* out_a    = out_s    + 196608;          // 12*512*2048
    float* out_asd  = out_a    + 12582912;
    float* out_apts = out_asd  + 12582912;

    dim3 b256(256);
    // Weight transposes into packed Bt layouts
    transpose_w_kernel<<<dim3(12,  6), b256, 0, stream>>>(W_q,   Wt_qc,              384, 192);
    transpose_w_kernel<<<dim3(12,  5), b256, 0, stream>>>(W_qp,  Wt_qc  + 192 * 384, 384, 144);
    transpose_w_kernel<<<dim3(12, 12), b256, 0, stream>>>(W_kv,  Wt_kvc,             384, 384);
    transpose_w_kernel<<<dim3(12, 14), b256, 0, stream>>>(W_kvp, Wt_kvc + 384 * 384, 384, 432);
    transpose_w_kernel<<<dim3(18, 12), b256, 0, stream>>>(W_out, Wt_out,             576, 384);
    // Projections via MFMA split-bf16
    mfma_gemm_bt_kernel<<<dim3(16, 11), dim3(64), 0, stream>>>(s_dst, Wt_qc,  nullptr, qcat,  LD, QCW, CS);
    mfma_gemm_bt_kernel<<<dim3(64, 26), dim3(64), 0, stream>>>(s_src, Wt_kvc, nullptr, kvcat, LS, KVW, CS);
    // Rotations + squared norms (src writes transposed) + kv transpose
    rot_dst_kernel<<<LD, 64, 0, stream>>>(qcat, R_dst, t_dst, qp_rot, sq_q);
    rot_src_kernel<<<LS, 192, 0, stream>>>(kvcat, R_src, t_src, kpT, vAllT, sqkT);
    transpose_kv_kernel<<<dim3(32, 12), b256, 0, stream>>>(kvcat, kT, vAllT);
    // Scores + softmax (+ a_sd, a_pts, a outputs)
    score_softmax_kernel<<<dim3(LD / 4, NH), b256, 0, stream>>>(
        qcat, kT, qp_rot, kpT, sq_q, sqkT, dst_mask, src_mask, head_w,
        out_a, out_asd, out_apts);
    // Zero accumulators (o_buf + opt_buf contiguous), then MFMA AV
    hipMemsetAsync(o_buf, 0, (size_t)(98304 + 147456) * sizeof(float), stream);
    av_mfma_kernel<<<dim3(LD / 16, NH, 4), dim3(64), 0, stream>>>(out_a, vAllT, o_buf, opt_buf);
    // Inverse rotation, norms, concat
    finalize_kernel<<<LD, 192, 0, stream>>>(o_buf, opt_buf, R_dst, t_dst, cat_buf);
    // Output projection via MFMA split-bf16 (+bias)
    mfma_gemm_bt_kernel<<<dim3(16, 12), dim3(64), 0, stream>>>(cat_buf, Wt_out, b_out, out_s, LD, CS, 576);
}